// Round 9
// baseline (973.163 us; speedup 1.0000x reference)
//
#include <hip/hip_runtime.h>

#define Nn 100000
#define Ee 800000
#define HC 128
#define HID 32
#define NHD 4
#define EDIM 16
#define Gg 256
#define NOUT 2
#define SLOPE 0.2f
#define BN_EPS 1e-5f
#define SCHUNK 1024
#define NSB 98   // ceil(Nn/SCHUNK)

typedef unsigned int u32;

// ---- tiny weight precompute: Kmat[16][12], kb[12]  (edge-path algebraic fold) ----
__global__ void compute_K(const float* __restrict__ efcW, const float* __restrict__ efcb,
                          const float* __restrict__ linE, const float* __restrict__ attE,
                          float* __restrict__ Kmat, float* __restrict__ kb)
{
  __shared__ float Msh[384];   // M[l][j][h] = sum_c linE[l][j][h*32+c]*attE[l][h][c]
  int t = threadIdx.x;
  if (t < 384) {
    int l = t >> 7, j = (t >> 2) & 31, h = t & 3;
    float m = 0.f;
    for (int c = 0; c < 32; ++c)
      m += linE[(l*32 + j)*128 + h*32 + c] * attE[(l*4 + h)*32 + c];
    Msh[l*128 + j*4 + h] = m;
  }
  __syncthreads();
  if (t < 192) {
    int k = t / 12, col = t % 12, l = col >> 2, h = col & 3;
    float acc = 0.f;
    for (int j = 0; j < 32; ++j)
      acc += efcW[k*32 + j] * Msh[l*128 + j*4 + h];
    Kmat[k*12 + col] = acc;
  } else if (t < 204) {
    int col = t - 192, l = col >> 2, h = col & 3;
    float acc = 0.f;
    for (int j = 0; j < 32; ++j)
      acc += efcb[j] * Msh[l*128 + j*4 + h];
    kb[col] = acc;
  }
}

// ---- CSR build ----
__global__ void k_hist(const int* __restrict__ dst, int* __restrict__ deg)
{
  int e = blockIdx.x * 256 + threadIdx.x;
  if (e < Ee) atomicAdd(&deg[dst[e]], 1);
}

__global__ void k_bsum(const int* __restrict__ deg, int* __restrict__ bsum)
{
  __shared__ int sh[256];
  int b = blockIdx.x, t = threadIdx.x;
  int s = 0;
  for (int i = t; i < SCHUNK; i += 256) {
    int idx = b*SCHUNK + i;
    if (idx < Nn) s += deg[idx];
  }
  sh[t] = s; __syncthreads();
  for (int o = 128; o; o >>= 1) { if (t < o) sh[t] += sh[t+o]; __syncthreads(); }
  if (!t) bsum[b] = sh[0];
}

__global__ void k_mid(const int* __restrict__ bsum, int* __restrict__ bpre, int* __restrict__ rowp)
{
  __shared__ int sh[NSB];
  int t = threadIdx.x;
  if (t < NSB) sh[t] = bsum[t];
  __syncthreads();
  if (!t) {
    int run = 0;
    for (int i = 0; i < NSB; ++i) { int v = sh[i]; sh[i] = run; run += v; }
    rowp[Nn] = run;
  }
  __syncthreads();
  if (t < NSB) bpre[t] = sh[t];
}

__global__ void k_scan(const int* __restrict__ deg, const int* __restrict__ bpre, int* __restrict__ rowp)
{
  __shared__ int sh[SCHUNK];
  int b = blockIdx.x, t = threadIdx.x;
  for (int i = t; i < SCHUNK; i += 256) {
    int idx = b*SCHUNK + i;
    sh[i] = (idx < Nn) ? deg[idx] : 0;
  }
  __syncthreads();
  if (!t) {
    int run = 0;
    for (int i = 0; i < SCHUNK; ++i) { int v = sh[i]; sh[i] = run; run += v; }
  }
  __syncthreads();
  int base = bpre[b];
  for (int i = t; i < SCHUNK; i += 256) {
    int idx = b*SCHUNK + i;
    if (idx < Nn) rowp[idx] = sh[i] + base;
  }
}

__global__ void k_fill(const int* __restrict__ src, const int* __restrict__ dst,
                       const int* __restrict__ rowp, int* __restrict__ fill,
                       int* __restrict__ src_s, int* __restrict__ perm)
{
  int e = blockIdx.x * 256 + threadIdx.x;
  if (e >= Ee) return;
  int d = dst[e];
  int pos = rowp[d] + atomicAdd(&fill[d], 1);
  src_s[pos] = src[e];
  perm[e] = pos;
}

// ---- GEMM: C[N,128] = BN?(A[N,128]) @ W[128,128], node_attn dots fused in epilogue
// launch_bounds(256,4): allow ~128 VGPR so the A-prefetch stays in registers.
// LDS exactly 32KB -> 5 blocks/CU. W-read bank aliasing is 2-way (free, m136).
__global__ __launch_bounds__(256, 4) void gemm_node(const float* __restrict__ A,
                                                 const float* __restrict__ W,
                                                 float* __restrict__ C,
                                                 const float* __restrict__ bnsum,
                                                 const float* __restrict__ bnsq,
                                                 const float* __restrict__ gammaL,
                                                 const float* __restrict__ betaL,
                                                 int apply_bn,
                                                 const float* __restrict__ aS,
                                                 const float* __restrict__ aD,
                                                 float* __restrict__ as_,
                                                 float* __restrict__ ad_)
{
  __shared__ float Wh[HC][64];   // 128 k x 64 cols staged; 32768 B
  __shared__ float sc_[HC], sh_[HC];
  int t = threadIdx.x;
  int hf = blockIdx.x & 1;
  int row0 = (blockIdx.x >> 1) * 128;
  for (int i = t; i < HC*16; i += 256) {
    int k = i >> 4, c4 = i & 15;
    *(float4*)&Wh[k][c4*4] = *(const float4*)(W + (size_t)k*HC + hf*64 + c4*4);
  }
  if (t < HC) {
    if (apply_bn) {
      float mu  = bnsum[t] * (1.f / Nn);
      float var = bnsq[t] * (1.f / Nn) - mu * mu;
      float s = rsqrtf(var + BN_EPS) * gammaL[t];
      sc_[t] = s;
      sh_[t] = betaL[t] - mu * s;
    } else { sc_[t] = 1.f; sh_[t] = 0.f; }
  }
  __syncthreads();
  int cg = t & 7, r = t >> 3;   // cols hf*64 + cg*8 .. +7 ; rows r+32i
  int rows[4];
  #pragma unroll
  for (int i = 0; i < 4; ++i) {
    int rr = row0 + r + 32*i;
    rows[i] = (rr < Nn) ? rr : (Nn - 1);
  }
  float4 acc[4][2];
  #pragma unroll
  for (int i = 0; i < 4; ++i) {
    acc[i][0] = make_float4(0.f,0.f,0.f,0.f);
    acc[i][1] = make_float4(0.f,0.f,0.f,0.f);
  }
  float4 a[4];
  #pragma unroll
  for (int i = 0; i < 4; ++i) a[i] = *(const float4*)(A + (size_t)rows[i]*HC);
  if (apply_bn) {
    for (int k4 = 0; k4 < 32; ++k4) {
      float4 an[4];
      if (k4 < 31) {
        #pragma unroll
        for (int i = 0; i < 4; ++i)
          an[i] = *(const float4*)(A + (size_t)rows[i]*HC + (k4+1)*4);
      }
      float4 s4 = *(const float4*)&sc_[k4*4];
      float4 h4 = *(const float4*)&sh_[k4*4];
      float4 w0[4], w1[4];
      #pragma unroll
      for (int j = 0; j < 4; ++j) {
        w0[j] = *(const float4*)&Wh[k4*4 + j][cg*8];
        w1[j] = *(const float4*)&Wh[k4*4 + j][cg*8 + 4];
      }
      #pragma unroll
      for (int i = 0; i < 4; ++i) {
        float4 av = a[i];
        av.x = fmaxf(av.x*s4.x + h4.x, 0.f);
        av.y = fmaxf(av.y*s4.y + h4.y, 0.f);
        av.z = fmaxf(av.z*s4.z + h4.z, 0.f);
        av.w = fmaxf(av.w*s4.w + h4.w, 0.f);
        acc[i][0].x += av.x*w0[0].x + av.y*w0[1].x + av.z*w0[2].x + av.w*w0[3].x;
        acc[i][0].y += av.x*w0[0].y + av.y*w0[1].y + av.z*w0[2].y + av.w*w0[3].y;
        acc[i][0].z += av.x*w0[0].z + av.y*w0[1].z + av.z*w0[2].z + av.w*w0[3].z;
        acc[i][0].w += av.x*w0[0].w + av.y*w0[1].w + av.z*w0[2].w + av.w*w0[3].w;
        acc[i][1].x += av.x*w1[0].x + av.y*w1[1].x + av.z*w1[2].x + av.w*w1[3].x;
        acc[i][1].y += av.x*w1[0].y + av.y*w1[1].y + av.z*w1[2].y + av.w*w1[3].y;
        acc[i][1].z += av.x*w1[0].z + av.y*w1[1].z + av.z*w1[2].z + av.w*w1[3].z;
        acc[i][1].w += av.x*w1[0].w + av.y*w1[1].w + av.z*w1[2].w + av.w*w1[3].w;
      }
      #pragma unroll
      for (int i = 0; i < 4; ++i) a[i] = an[i];
    }
  } else {
    for (int k4 = 0; k4 < 32; ++k4) {
      float4 an[4];
      if (k4 < 31) {
        #pragma unroll
        for (int i = 0; i < 4; ++i)
          an[i] = *(const float4*)(A + (size_t)rows[i]*HC + (k4+1)*4);
      }
      float4 w0[4], w1[4];
      #pragma unroll
      for (int j = 0; j < 4; ++j) {
        w0[j] = *(const float4*)&Wh[k4*4 + j][cg*8];
        w1[j] = *(const float4*)&Wh[k4*4 + j][cg*8 + 4];
      }
      #pragma unroll
      for (int i = 0; i < 4; ++i) {
        float4 av = a[i];
        acc[i][0].x += av.x*w0[0].x + av.y*w0[1].x + av.z*w0[2].x + av.w*w0[3].x;
        acc[i][0].y += av.x*w0[0].y + av.y*w0[1].y + av.z*w0[2].y + av.w*w0[3].y;
        acc[i][0].z += av.x*w0[0].z + av.y*w0[1].z + av.z*w0[2].z + av.w*w0[3].z;
        acc[i][0].w += av.x*w0[0].w + av.y*w0[1].w + av.z*w0[2].w + av.w*w0[3].w;
        acc[i][1].x += av.x*w1[0].x + av.y*w1[1].x + av.z*w1[2].x + av.w*w1[3].x;
        acc[i][1].y += av.x*w1[0].y + av.y*w1[1].y + av.z*w1[2].y + av.w*w1[3].y;
        acc[i][1].z += av.x*w1[0].z + av.y*w1[1].z + av.z*w1[2].z + av.w*w1[3].z;
        acc[i][1].w += av.x*w1[0].w + av.y*w1[1].w + av.z*w1[2].w + av.w*w1[3].w;
      }
      #pragma unroll
      for (int i = 0; i < 4; ++i) a[i] = an[i];
    }
  }
  #pragma unroll
  for (int i = 0; i < 4; ++i) {
    int row = row0 + r + 32*i;
    if (row < Nn) {
      *(float4*)(C + (size_t)row*HC + hf*64 + cg*8)     = acc[i][0];
      *(float4*)(C + (size_t)row*HC + hf*64 + cg*8 + 4) = acc[i][1];
    }
  }
  // fused node_attn: this col-half covers heads hf*2 + (cg>>2); 8-col group is within one head
  float4 aS0 = *(const float4*)(aS + hf*64 + cg*8);
  float4 aS1 = *(const float4*)(aS + hf*64 + cg*8 + 4);
  float4 aD0 = *(const float4*)(aD + hf*64 + cg*8);
  float4 aD1 = *(const float4*)(aD + hf*64 + cg*8 + 4);
  #pragma unroll
  for (int i = 0; i < 4; ++i) {
    float s1 = acc[i][0].x*aS0.x + acc[i][0].y*aS0.y + acc[i][0].z*aS0.z + acc[i][0].w*aS0.w
             + acc[i][1].x*aS1.x + acc[i][1].y*aS1.y + acc[i][1].z*aS1.z + acc[i][1].w*aS1.w;
    float s2 = acc[i][0].x*aD0.x + acc[i][0].y*aD0.y + acc[i][0].z*aD0.z + acc[i][0].w*aD0.w
             + acc[i][1].x*aD1.x + acc[i][1].y*aD1.y + acc[i][1].z*aD1.z + acc[i][1].w*aD1.w;
    s1 += __shfl_xor(s1, 1); s1 += __shfl_xor(s1, 2);
    s2 += __shfl_xor(s2, 1); s2 += __shfl_xor(s2, 2);
    if ((cg & 3) == 0) {
      int row = row0 + r + 32*i;
      if (row < Nn) {
        int h = hf*2 + (cg >> 2);
        as_[row*NHD + h] = s1;
        ad_[row*NHD + h] = s2;
      }
    }
  }
}

// alpha -> leaky -> w=exp(alpha), scattered into dst-sorted position
__global__ void edge_alpha(const int* __restrict__ src, const int* __restrict__ dst,
                           const float* __restrict__ eattr, const float* __restrict__ Kmat,
                           const float* __restrict__ kb, int l,
                           const float* __restrict__ as_, const float* __restrict__ ad_,
                           const int* __restrict__ perm, float* __restrict__ ew_s)
{
  int e = blockIdx.x * 256 + threadIdx.x;
  if (e >= Ee) return;
  const float4* p = (const float4*)(eattr + (size_t)e * EDIM);
  float ea[16];
  #pragma unroll
  for (int q = 0; q < 4; ++q) {
    float4 v = p[q];
    ea[q*4+0] = v.x; ea[q*4+1] = v.y; ea[q*4+2] = v.z; ea[q*4+3] = v.w;
  }
  float al[4];
  #pragma unroll
  for (int h = 0; h < 4; ++h) al[h] = kb[l*4 + h];
  #pragma unroll
  for (int k = 0; k < 16; ++k) {
    float v = ea[k];
    #pragma unroll
    for (int h = 0; h < 4; ++h) al[h] += v * Kmat[k*12 + l*4 + h];
  }
  int s = src[e], d = dst[e];
  float4 sv = *(const float4*)(as_ + (size_t)s * 4);
  float4 dv = *(const float4*)(ad_ + (size_t)d * 4);
  float4 a;
  a.x = al[0] + sv.x + dv.x; a.y = al[1] + sv.y + dv.y;
  a.z = al[2] + sv.z + dv.z; a.w = al[3] + sv.w + dv.w;
  a.x = (a.x > 0.f) ? a.x : SLOPE * a.x;
  a.y = (a.y > 0.f) ? a.y : SLOPE * a.y;
  a.z = (a.z > 0.f) ? a.z : SLOPE * a.z;
  a.w = (a.w > 0.f) ? a.w : SLOPE * a.w;
  float4 w;
  w.x = __expf(a.x); w.y = __expf(a.y); w.z = __expf(a.z); w.w = __expf(a.w);
  int pos = perm[e];
  *(float4*)(ew_s + (size_t)pos * 4) = w;
}

// CSR aggregation: 32 thr/node (float4 per thread), 8 nodes/block, unroll-8 edges
__global__ __launch_bounds__(256) void aggregate(const int* __restrict__ rowp, const int* __restrict__ src_s,
                                                 const float* __restrict__ ew_s, const float* __restrict__ xl,
                                                 const float* __restrict__ bias, float* __restrict__ outp)
{
  int n = blockIdx.x * 8 + (threadIdx.x >> 5);
  if (n >= Nn) return;
  int c4 = threadIdx.x & 31;        // channels c4*4 .. c4*4+3 (single head: h = c4>>3)
  int h = c4 >> 3;
  int beg = rowp[n], end = rowp[n+1];
  float4 acc = make_float4(0.f,0.f,0.f,0.f);
  float wsum = 0.f;
  int i = beg;
  for (; i + 8 <= end; i += 8) {
    int s[8]; float w[8]; float4 v[8];
    #pragma unroll
    for (int j = 0; j < 8; ++j) s[j] = src_s[i+j];
    #pragma unroll
    for (int j = 0; j < 8; ++j) w[j] = ew_s[(size_t)(i+j)*4 + h];
    #pragma unroll
    for (int j = 0; j < 8; ++j) v[j] = *(const float4*)(xl + (size_t)s[j] * HC + c4*4);
    #pragma unroll
    for (int j = 0; j < 8; ++j) {
      acc.x += w[j]*v[j].x; acc.y += w[j]*v[j].y;
      acc.z += w[j]*v[j].z; acc.w += w[j]*v[j].w;
      wsum += w[j];
    }
  }
  for (; i + 4 <= end; i += 4) {
    int s0 = src_s[i], s1 = src_s[i+1], s2 = src_s[i+2], s3 = src_s[i+3];
    float w0 = ew_s[(size_t)(i+0)*4 + h];
    float w1 = ew_s[(size_t)(i+1)*4 + h];
    float w2 = ew_s[(size_t)(i+2)*4 + h];
    float w3 = ew_s[(size_t)(i+3)*4 + h];
    float4 v0 = *(const float4*)(xl + (size_t)s0 * HC + c4*4);
    float4 v1 = *(const float4*)(xl + (size_t)s1 * HC + c4*4);
    float4 v2 = *(const float4*)(xl + (size_t)s2 * HC + c4*4);
    float4 v3 = *(const float4*)(xl + (size_t)s3 * HC + c4*4);
    acc.x += w0*v0.x + w1*v1.x + w2*v2.x + w3*v3.x;
    acc.y += w0*v0.y + w1*v1.y + w2*v2.y + w3*v3.y;
    acc.z += w0*v0.z + w1*v1.z + w2*v2.z + w3*v3.z;
    acc.w += w0*v0.w + w1*v1.w + w2*v2.w + w3*v3.w;
    wsum += w0 + w1 + w2 + w3;
  }
  for (; i < end; ++i) {
    int s = src_s[i];
    float w = ew_s[(size_t)i*4 + h];
    float4 v = *(const float4*)(xl + (size_t)s * HC + c4*4);
    acc.x += w*v.x; acc.y += w*v.y; acc.z += w*v.z; acc.w += w*v.w;
    wsum += w;
  }
  float inv = 1.f / (wsum + 1e-16f);
  float4 b4 = *(const float4*)(bias + c4*4);
  float4 o;
  o.x = acc.x*inv + b4.x; o.y = acc.y*inv + b4.y;
  o.z = acc.z*inv + b4.z; o.w = acc.w*inv + b4.w;
  *(float4*)(outp + (size_t)n * HC + c4*4) = o;
}

__global__ void bn_reduce(const float* __restrict__ A, float* __restrict__ bnsum, float* __restrict__ bnsq)
{
  __shared__ float ss[256], sq[256];
  int t = threadIdx.x;
  int c = t & 127, hh = t >> 7;
  float s = 0.f, q = 0.f;
  for (int n = blockIdx.x * 2 + hh; n < Nn; n += gridDim.x * 2) {
    float v = A[(size_t)n * HC + c];
    s += v; q += v * v;
  }
  ss[t] = s; sq[t] = q;
  __syncthreads();
  if (t < 128) {
    atomicAdd(&bnsum[c], ss[t] + ss[t+128]);
    atomicAdd(&bnsq[c],  sq[t] + sq[t+128]);
  }
}

// global mean pool with BN+ReLU of final layer fused
__global__ void pool_kernel(const float* __restrict__ A, const int* __restrict__ batch,
                            const float* __restrict__ bnsum, const float* __restrict__ bnsq,
                            const float* __restrict__ gammaL, const float* __restrict__ betaL,
                            float* __restrict__ pool)
{
  int t = threadIdx.x;
  int c = t & 127, hh = t >> 7;
  float mu  = bnsum[c] * (1.f / Nn);
  float var = bnsq[c] * (1.f / Nn) - mu * mu;
  float s_ = rsqrtf(var + BN_EPS) * gammaL[c];
  float sh_ = betaL[c] - mu * s_;
  int n0 = blockIdx.x * 256;
  float accv = 0.f; int curg = -1;
  for (int i = hh; i < 256; i += 2) {
    int n = n0 + i;
    if (n >= Nn) break;
    int g = batch[n];
    if (g != curg) {
      if (curg >= 0) atomicAdd(&pool[(size_t)curg * HC + c], accv);
      curg = g; accv = 0.f;
    }
    accv += fmaxf(A[(size_t)n * HC + c] * s_ + sh_, 0.f);
  }
  if (curg >= 0) atomicAdd(&pool[(size_t)curg * HC + c], accv);
}

// batch is sorted: cnt[g] = lower_bound(g+1) - lower_bound(g); fused into FC
__device__ __forceinline__ int lbound(const int* __restrict__ a, int n, int key)
{
  int lo = 0, hi = n;
  while (lo < hi) {
    int mid = (lo + hi) >> 1;
    if (a[mid] < key) lo = mid + 1; else hi = mid;
  }
  return lo;
}

__global__ void final_fc(const float* __restrict__ pool, const int* __restrict__ batch,
                         const float* __restrict__ fcW, const float* __restrict__ fcb,
                         float* __restrict__ out)
{
  int t = blockIdx.x * 256 + threadIdx.x;
  if (t >= Gg * NOUT) return;
  int g = t >> 1, o = t & 1;
  int lo = lbound(batch, Nn, g);
  int hi = lbound(batch, Nn, g + 1);
  float cn = fmaxf((float)(hi - lo), 1.f);
  float acc = 0.f;
  for (int k = 0; k < HC; ++k)
    acc += pool[(size_t)g * HC + k] * fcW[k * NOUT + o];
  out[t] = acc / cn + fcb[o];
}

extern "C" void kernel_launch(void* const* d_in, const int* in_sizes, int n_in,
                              void* d_out, int out_size, void* d_ws, size_t ws_size,
                              hipStream_t stream)
{
  const float* x      = (const float*)d_in[0];
  const int*   eidx   = (const int*)d_in[1];
  const float* eattr  = (const float*)d_in[2];
  const int*   batch  = (const int*)d_in[3];
  const float* efcW   = (const float*)d_in[4];
  const float* efcb   = (const float*)d_in[5];
  const float* Wall   = (const float*)d_in[6];
  const float* attS   = (const float*)d_in[7];
  const float* attD   = (const float*)d_in[8];
  const float* attE   = (const float*)d_in[9];
  const float* linE   = (const float*)d_in[10];
  const float* biases = (const float*)d_in[11];
  const float* gamma  = (const float*)d_in[12];
  const float* beta   = (const float*)d_in[13];
  const float* fcW    = (const float*)d_in[14];
  const float* fcb    = (const float*)d_in[15];
  float* out = (float*)d_out;

  const int* src = eidx;
  const int* dst = eidx + Ee;

  float* ws    = (float*)d_ws;
  float* bufA  = ws;                            // N*128
  float* bufB  = bufA + (size_t)Nn*HC;          // N*128
  float* as_   = bufB + (size_t)Nn*HC;          // N*4
  float* ad_   = as_ + (size_t)Nn*NHD;          // N*4
  float* ew_s  = ad_ + (size_t)Nn*NHD;          // E*4 (16B aligned)
  float* Kmat  = ew_s + (size_t)Ee*NHD;         // 192
  float* kb    = Kmat + 192;                    // 16
  float* bnsum = kb + 16;                       // 128
  float* bnsq  = bnsum + 128;                   // 128
  float* pool  = bnsq + 128;                    // G*128
  int*   rowp  = (int*)(pool + (size_t)Gg*HC);  // N+1
  int*   deg   = rowp + (Nn + 1);               // N
  int*   fill  = deg + Nn;                      // N  (deg..fill one memset)
  int*   src_s = fill + Nn;                     // E
  int*   perm  = src_s + Ee;                    // E
  int*   bsum  = perm + Ee;                     // NSB
  int*   bpre  = bsum + 128;                    // NSB

  compute_K<<<1, 512, 0, stream>>>(efcW, efcb, linE, attE, Kmat, kb);

  // CSR build (reused across all 3 layers)
  hipMemsetAsync(deg, 0, 2*Nn*sizeof(int), stream);
  k_hist<<<(Ee + 255)/256, 256, 0, stream>>>(dst, deg);
  k_bsum<<<NSB, 256, 0, stream>>>(deg, bsum);
  k_mid<<<1, 128, 0, stream>>>(bsum, bpre, rowp);
  k_scan<<<NSB, 256, 0, stream>>>(deg, bpre, rowp);
  k_fill<<<(Ee + 255)/256, 256, 0, stream>>>(src, dst, rowp, fill, src_s, perm);

  for (int l = 0; l < 3; ++l) {
    const float* Ain = (l == 0) ? x : bufA;
    gemm_node<<<((Nn + 127)/128)*2, 256, 0, stream>>>(Ain, Wall + (size_t)l*HC*HC, bufB,
                                                      bnsum, bnsq, gamma + (l-1)*HC, beta + (l-1)*HC,
                                                      (l > 0) ? 1 : 0,
                                                      attS + l*HC, attD + l*HC, as_, ad_);
    edge_alpha<<<(Ee + 255)/256, 256, 0, stream>>>(src, dst, eattr, Kmat, kb, l, as_, ad_, perm, ew_s);
    aggregate<<<(Nn + 7)/8, 256, 0, stream>>>(rowp, src_s, ew_s, bufB, biases + l*HC, bufA);
    hipMemsetAsync(bnsum, 0, 256*sizeof(float), stream);
    bn_reduce<<<256, 256, 0, stream>>>(bufA, bnsum, bnsq);
  }

  hipMemsetAsync(pool, 0, (size_t)Gg*HC*sizeof(float), stream);
  pool_kernel<<<(Nn + 255)/256, 256, 0, stream>>>(bufA, batch, bnsum, bnsq, gamma + 2*HC, beta + 2*HC, pool);
  final_fc<<<2, 256, 0, stream>>>(pool, batch, fcW, fcb, out);
}

// Round 10
// 928.108 us; speedup vs baseline: 1.0485x; 1.0485x over previous
//
#include <hip/hip_runtime.h>

#define Nn 100000
#define Ee 800000
#define HC 128
#define HID 32
#define NHD 4
#define EDIM 16
#define Gg 256
#define NOUT 2
#define SLOPE 0.2f
#define BN_EPS 1e-5f
#define SCHUNK 1024
#define NSB 98   // ceil(Nn/SCHUNK)

typedef unsigned int u32;
typedef short v8s __attribute__((ext_vector_type(8)));
typedef float v4f __attribute__((ext_vector_type(4)));

union PkAB { u32 u[4]; v8s v; };

// round-to-nearest-even f32 -> bf16 bits
__device__ __forceinline__ u32 bf16rne(float x)
{
  u32 b = __float_as_uint(x);
  return (b + 0x7FFFu + ((b >> 16) & 1u)) >> 16;
}
// pack x into (hi bf16 | lo bf16 << 16)
__device__ __forceinline__ u32 packsplit(float x)
{
  u32 hb = bf16rne(x);
  float hf = __uint_as_float(hb << 16);
  u32 lb = bf16rne(x - hf);
  return hb | (lb << 16);
}

// ---- tiny weight precompute: Kmat[16][12], kb[12]  (edge-path algebraic fold) ----
__global__ void compute_K(const float* __restrict__ efcW, const float* __restrict__ efcb,
                          const float* __restrict__ linE, const float* __restrict__ attE,
                          float* __restrict__ Kmat, float* __restrict__ kb)
{
  __shared__ float Msh[384];   // M[l][j][h] = sum_c linE[l][j][h*32+c]*attE[l][h][c]
  int t = threadIdx.x;
  if (t < 384) {
    int l = t >> 7, j = (t >> 2) & 31, h = t & 3;
    float m = 0.f;
    for (int c = 0; c < 32; ++c)
      m += linE[(l*32 + j)*128 + h*32 + c] * attE[(l*4 + h)*32 + c];
    Msh[l*128 + j*4 + h] = m;
  }
  __syncthreads();
  if (t < 192) {
    int k = t / 12, col = t % 12, l = col >> 2, h = col & 3;
    float acc = 0.f;
    for (int j = 0; j < 32; ++j)
      acc += efcW[k*32 + j] * Msh[l*128 + j*4 + h];
    Kmat[k*12 + col] = acc;
  } else if (t < 204) {
    int col = t - 192, l = col >> 2, h = col & 3;
    float acc = 0.f;
    for (int j = 0; j < 32; ++j)
      acc += efcb[j] * Msh[l*128 + j*4 + h];
    kb[col] = acc;
  }
}

// ---- W -> split-bf16 MFMA B-fragment layout (once) ----
// frag pos: n=nt*16+col, k=ks*32+quad*8+j ; u32 idx = ((((l*8+nt)*4+ks)*2+half)*64 + quad*16+col)*4 + (j&3)
__global__ void w_split(const float* __restrict__ Wall, u32* __restrict__ Wf)
{
  int tid = blockIdx.x * 256 + threadIdx.x;
  if (tid >= 3*HC*HC) return;
  int l = tid / (HC*HC);
  int rem = tid - l*HC*HC;
  int k = rem >> 7, n = rem & 127;
  u32 p = packsplit(Wall[tid]);
  int nt = n >> 4, col = n & 15;
  int ks = k >> 5, kin = k & 31, q = kin >> 3, j = kin & 7;
  int half = j >> 2, j4 = j & 3;
  int idx = ((((l*8 + nt)*4 + ks)*2 + half)*64 + q*16 + col)*4 + j4;
  Wf[idx] = p;
}

// ---- CSR build ----
__global__ void k_hist(const int* __restrict__ dst, int* __restrict__ deg)
{
  int e = blockIdx.x * 256 + threadIdx.x;
  if (e < Ee) atomicAdd(&deg[dst[e]], 1);
}

__global__ void k_bsum(const int* __restrict__ deg, int* __restrict__ bsum)
{
  __shared__ int sh[256];
  int b = blockIdx.x, t = threadIdx.x;
  int s = 0;
  for (int i = t; i < SCHUNK; i += 256) {
    int idx = b*SCHUNK + i;
    if (idx < Nn) s += deg[idx];
  }
  sh[t] = s; __syncthreads();
  for (int o = 128; o; o >>= 1) { if (t < o) sh[t] += sh[t+o]; __syncthreads(); }
  if (!t) bsum[b] = sh[0];
}

__global__ void k_mid(const int* __restrict__ bsum, int* __restrict__ bpre, int* __restrict__ rowp)
{
  __shared__ int sh[NSB];
  int t = threadIdx.x;
  if (t < NSB) sh[t] = bsum[t];
  __syncthreads();
  if (!t) {
    int run = 0;
    for (int i = 0; i < NSB; ++i) { int v = sh[i]; sh[i] = run; run += v; }
    rowp[Nn] = run;
  }
  __syncthreads();
  if (t < NSB) bpre[t] = sh[t];
}

__global__ void k_scan(const int* __restrict__ deg, const int* __restrict__ bpre, int* __restrict__ rowp)
{
  __shared__ int sh[SCHUNK];
  int b = blockIdx.x, t = threadIdx.x;
  for (int i = t; i < SCHUNK; i += 256) {
    int idx = b*SCHUNK + i;
    sh[i] = (idx < Nn) ? deg[idx] : 0;
  }
  __syncthreads();
  if (!t) {
    int run = 0;
    for (int i = 0; i < SCHUNK; ++i) { int v = sh[i]; sh[i] = run; run += v; }
  }
  __syncthreads();
  int base = bpre[b];
  for (int i = t; i < SCHUNK; i += 256) {
    int idx = b*SCHUNK + i;
    if (idx < Nn) rowp[idx] = sh[i] + base;
  }
}

__global__ void k_fill(const int* __restrict__ src, const int* __restrict__ dst,
                       const int* __restrict__ rowp, int* __restrict__ fill,
                       int* __restrict__ src_s, int* __restrict__ perm)
{
  int e = blockIdx.x * 256 + threadIdx.x;
  if (e >= Ee) return;
  int d = dst[e];
  int pos = rowp[d] + atomicAdd(&fill[d], 1);
  src_s[pos] = src[e];
  perm[e] = pos;
}

// ---- BN(+ReLU) of prev layer + split-pack to bf16 hi/lo, in-place safe (same-address) ----
__global__ void split_bn(const float* src, u32* dst,
                         const float* __restrict__ bnsum, const float* __restrict__ bnsq,
                         const float* __restrict__ gammaL, const float* __restrict__ betaL,
                         int apply_bn)
{
  int idx = blockIdx.x * 256 + threadIdx.x;    // one float4 per thread
  if (idx >= Nn*HC/4) return;
  float4 v = ((const float4*)src)[idx];
  if (apply_bn) {
    int c = (idx * 4) & 127;
    float s0, t0, s1, t1, s2, t2, s3, t3;
    {
      float mu  = bnsum[c+0] * (1.f/Nn); float var = bnsq[c+0] * (1.f/Nn) - mu*mu;
      s0 = rsqrtf(var + BN_EPS) * gammaL[c+0]; t0 = betaL[c+0] - mu * s0;
    }
    {
      float mu  = bnsum[c+1] * (1.f/Nn); float var = bnsq[c+1] * (1.f/Nn) - mu*mu;
      s1 = rsqrtf(var + BN_EPS) * gammaL[c+1]; t1 = betaL[c+1] - mu * s1;
    }
    {
      float mu  = bnsum[c+2] * (1.f/Nn); float var = bnsq[c+2] * (1.f/Nn) - mu*mu;
      s2 = rsqrtf(var + BN_EPS) * gammaL[c+2]; t2 = betaL[c+2] - mu * s2;
    }
    {
      float mu  = bnsum[c+3] * (1.f/Nn); float var = bnsq[c+3] * (1.f/Nn) - mu*mu;
      s3 = rsqrtf(var + BN_EPS) * gammaL[c+3]; t3 = betaL[c+3] - mu * s3;
    }
    v.x = fmaxf(v.x*s0 + t0, 0.f);
    v.y = fmaxf(v.y*s1 + t1, 0.f);
    v.z = fmaxf(v.z*s2 + t2, 0.f);
    v.w = fmaxf(v.w*s3 + t3, 0.f);
  }
  uint4 o;
  o.x = packsplit(v.x); o.y = packsplit(v.y);
  o.z = packsplit(v.z); o.w = packsplit(v.w);
  ((uint4*)dst)[idx] = o;
}

// ---- MFMA GEMM: C[N,128] = A[N,128] @ W[128,128]; split-bf16 (3 mfma per product)
// Apk: packed (hi|lo<<16) u32 [N][128].  Wf: fragment-ordered packed W for this layer.
// attn dots fused in epilogue.
__global__ __launch_bounds__(256, 2) void gemm_mfma(const u32* __restrict__ Apk,
                                                    const u32* __restrict__ Wf,
                                                    float* __restrict__ C,
                                                    const float* __restrict__ aS,
                                                    const float* __restrict__ aD,
                                                    float* __restrict__ as_,
                                                    float* __restrict__ ad_)
{
  int t = threadIdx.x;
  int w = t >> 6, lane = t & 63;
  int col = lane & 15, q = lane >> 4;
  int rbase = blockIdx.x * 128 + w * 32;

  v4f acc[2][8];
  #pragma unroll
  for (int mt = 0; mt < 2; ++mt)
    #pragma unroll
    for (int nt = 0; nt < 8; ++nt)
      acc[mt][nt] = (v4f){0.f, 0.f, 0.f, 0.f};

  const uint4* Wf4 = (const uint4*)Wf;

  for (int ks = 0; ks < 4; ++ks) {
    // A fragments (hi & lo) for 2 m-tiles
    PkAB Ah[2], Al[2];
    #pragma unroll
    for (int mt = 0; mt < 2; ++mt) {
      int ar = rbase + mt*16 + col;
      if (ar >= Nn) ar = Nn - 1;
      const uint4* pa = (const uint4*)(Apk + (size_t)ar*HC + ks*32 + q*8);
      uint4 r0 = pa[0], r1 = pa[1];
      Ah[mt].u[0] = (r0.x & 0xFFFFu) | (r0.y << 16);
      Al[mt].u[0] = (r0.x >> 16)     | (r0.y & 0xFFFF0000u);
      Ah[mt].u[1] = (r0.z & 0xFFFFu) | (r0.w << 16);
      Al[mt].u[1] = (r0.z >> 16)     | (r0.w & 0xFFFF0000u);
      Ah[mt].u[2] = (r1.x & 0xFFFFu) | (r1.y << 16);
      Al[mt].u[2] = (r1.x >> 16)     | (r1.y & 0xFFFF0000u);
      Ah[mt].u[3] = (r1.z & 0xFFFFu) | (r1.w << 16);
      Al[mt].u[3] = (r1.z >> 16)     | (r1.w & 0xFFFF0000u);
    }
    #pragma unroll
    for (int nt = 0; nt < 8; ++nt) {
      uint4 b0 = Wf4[((nt*4 + ks)*2 + 0)*64 + lane];
      uint4 b1 = Wf4[((nt*4 + ks)*2 + 1)*64 + lane];
      PkAB Bh, Bl;
      Bh.u[0] = (b0.x & 0xFFFFu) | (b0.y << 16);
      Bl.u[0] = (b0.x >> 16)     | (b0.y & 0xFFFF0000u);
      Bh.u[1] = (b0.z & 0xFFFFu) | (b0.w << 16);
      Bl.u[1] = (b0.z >> 16)     | (b0.w & 0xFFFF0000u);
      Bh.u[2] = (b1.x & 0xFFFFu) | (b1.y << 16);
      Bl.u[2] = (b1.x >> 16)     | (b1.y & 0xFFFF0000u);
      Bh.u[3] = (b1.z & 0xFFFFu) | (b1.w << 16);
      Bl.u[3] = (b1.z >> 16)     | (b1.w & 0xFFFF0000u);
      #pragma unroll
      for (int mt = 0; mt < 2; ++mt) {
        acc[mt][nt] = __builtin_amdgcn_mfma_f32_16x16x32_bf16(Ah[mt].v, Bh.v, acc[mt][nt], 0, 0, 0);
        acc[mt][nt] = __builtin_amdgcn_mfma_f32_16x16x32_bf16(Ah[mt].v, Bl.v, acc[mt][nt], 0, 0, 0);
        acc[mt][nt] = __builtin_amdgcn_mfma_f32_16x16x32_bf16(Al[mt].v, Bh.v, acc[mt][nt], 0, 0, 0);
      }
    }
  }

  // C store: row = rbase + mt*16 + q*4 + reg, col = nt*16 + (lane&15)
  #pragma unroll
  for (int mt = 0; mt < 2; ++mt) {
    #pragma unroll
    for (int reg = 0; reg < 4; ++reg) {
      int row = rbase + mt*16 + q*4 + reg;
      if (row < Nn) {
        #pragma unroll
        for (int nt = 0; nt < 8; ++nt)
          C[(size_t)row*HC + nt*16 + col] = acc[mt][nt][reg];
      }
    }
  }

  // fused attn dots: s1(row,h) = sum_c C[row][32h..32h+31] * aS[...]
  #pragma unroll
  for (int mt = 0; mt < 2; ++mt) {
    #pragma unroll
    for (int h = 0; h < 4; ++h) {
      float a0 = aS[32*h + col], a1 = aS[32*h + 16 + col];
      float d0 = aD[32*h + col], d1 = aD[32*h + 16 + col];
      #pragma unroll
      for (int reg = 0; reg < 4; ++reg) {
        float s1 = acc[mt][2*h][reg]*a0 + acc[mt][2*h+1][reg]*a1;
        float s2 = acc[mt][2*h][reg]*d0 + acc[mt][2*h+1][reg]*d1;
        s1 += __shfl_xor(s1, 1); s1 += __shfl_xor(s1, 2);
        s1 += __shfl_xor(s1, 4); s1 += __shfl_xor(s1, 8);
        s2 += __shfl_xor(s2, 1); s2 += __shfl_xor(s2, 2);
        s2 += __shfl_xor(s2, 4); s2 += __shfl_xor(s2, 8);
        if (col == 0) {
          int row = rbase + mt*16 + q*4 + reg;
          if (row < Nn) {
            as_[row*NHD + h] = s1;
            ad_[row*NHD + h] = s2;
          }
        }
      }
    }
  }
}

// alpha -> leaky -> w=exp(alpha), scattered into dst-sorted position
__global__ void edge_alpha(const int* __restrict__ src, const int* __restrict__ dst,
                           const float* __restrict__ eattr, const float* __restrict__ Kmat,
                           const float* __restrict__ kb, int l,
                           const float* __restrict__ as_, const float* __restrict__ ad_,
                           const int* __restrict__ perm, float* __restrict__ ew_s)
{
  int e = blockIdx.x * 256 + threadIdx.x;
  if (e >= Ee) return;
  const float4* p = (const float4*)(eattr + (size_t)e * EDIM);
  float ea[16];
  #pragma unroll
  for (int qq = 0; qq < 4; ++qq) {
    float4 v = p[qq];
    ea[qq*4+0] = v.x; ea[qq*4+1] = v.y; ea[qq*4+2] = v.z; ea[qq*4+3] = v.w;
  }
  float al[4];
  #pragma unroll
  for (int h = 0; h < 4; ++h) al[h] = kb[l*4 + h];
  #pragma unroll
  for (int k = 0; k < 16; ++k) {
    float v = ea[k];
    #pragma unroll
    for (int h = 0; h < 4; ++h) al[h] += v * Kmat[k*12 + l*4 + h];
  }
  int s = src[e], d = dst[e];
  float4 sv = *(const float4*)(as_ + (size_t)s * 4);
  float4 dv = *(const float4*)(ad_ + (size_t)d * 4);
  float4 a;
  a.x = al[0] + sv.x + dv.x; a.y = al[1] + sv.y + dv.y;
  a.z = al[2] + sv.z + dv.z; a.w = al[3] + sv.w + dv.w;
  a.x = (a.x > 0.f) ? a.x : SLOPE * a.x;
  a.y = (a.y > 0.f) ? a.y : SLOPE * a.y;
  a.z = (a.z > 0.f) ? a.z : SLOPE * a.z;
  a.w = (a.w > 0.f) ? a.w : SLOPE * a.w;
  float4 w;
  w.x = __expf(a.x); w.y = __expf(a.y); w.z = __expf(a.z); w.w = __expf(a.w);
  int pos = perm[e];
  *(float4*)(ew_s + (size_t)pos * 4) = w;
}

// CSR aggregation: 32 thr/node (float4 per thread), 8 nodes/block, unroll-8 edges
__global__ __launch_bounds__(256) void aggregate(const int* __restrict__ rowp, const int* __restrict__ src_s,
                                                 const float* __restrict__ ew_s, const float* __restrict__ xl,
                                                 const float* __restrict__ bias, float* __restrict__ outp)
{
  int n = blockIdx.x * 8 + (threadIdx.x >> 5);
  if (n >= Nn) return;
  int c4 = threadIdx.x & 31;
  int h = c4 >> 3;
  int beg = rowp[n], end = rowp[n+1];
  float4 acc = make_float4(0.f,0.f,0.f,0.f);
  float wsum = 0.f;
  int i = beg;
  for (; i + 8 <= end; i += 8) {
    int s[8]; float w[8]; float4 v[8];
    #pragma unroll
    for (int j = 0; j < 8; ++j) s[j] = src_s[i+j];
    #pragma unroll
    for (int j = 0; j < 8; ++j) w[j] = ew_s[(size_t)(i+j)*4 + h];
    #pragma unroll
    for (int j = 0; j < 8; ++j) v[j] = *(const float4*)(xl + (size_t)s[j] * HC + c4*4);
    #pragma unroll
    for (int j = 0; j < 8; ++j) {
      acc.x += w[j]*v[j].x; acc.y += w[j]*v[j].y;
      acc.z += w[j]*v[j].z; acc.w += w[j]*v[j].w;
      wsum += w[j];
    }
  }
  for (; i + 4 <= end; i += 4) {
    int s0 = src_s[i], s1 = src_s[i+1], s2 = src_s[i+2], s3 = src_s[i+3];
    float w0 = ew_s[(size_t)(i+0)*4 + h];
    float w1 = ew_s[(size_t)(i+1)*4 + h];
    float w2 = ew_s[(size_t)(i+2)*4 + h];
    float w3 = ew_s[(size_t)(i+3)*4 + h];
    float4 v0 = *(const float4*)(xl + (size_t)s0 * HC + c4*4);
    float4 v1 = *(const float4*)(xl + (size_t)s1 * HC + c4*4);
    float4 v2 = *(const float4*)(xl + (size_t)s2 * HC + c4*4);
    float4 v3 = *(const float4*)(xl + (size_t)s3 * HC + c4*4);
    acc.x += w0*v0.x + w1*v1.x + w2*v2.x + w3*v3.x;
    acc.y += w0*v0.y + w1*v1.y + w2*v2.y + w3*v3.y;
    acc.z += w0*v0.z + w1*v1.z + w2*v2.z + w3*v3.z;
    acc.w += w0*v0.w + w1*v1.w + w2*v2.w + w3*v3.w;
    wsum += w0 + w1 + w2 + w3;
  }
  for (; i < end; ++i) {
    int s = src_s[i];
    float w = ew_s[(size_t)i*4 + h];
    float4 v = *(const float4*)(xl + (size_t)s * HC + c4*4);
    acc.x += w*v.x; acc.y += w*v.y; acc.z += w*v.z; acc.w += w*v.w;
    wsum += w;
  }
  float inv = 1.f / (wsum + 1e-16f);
  float4 b4 = *(const float4*)(bias + c4*4);
  float4 o;
  o.x = acc.x*inv + b4.x; o.y = acc.y*inv + b4.y;
  o.z = acc.z*inv + b4.z; o.w = acc.w*inv + b4.w;
  *(float4*)(outp + (size_t)n * HC + c4*4) = o;
}

__global__ void bn_reduce(const float* __restrict__ A, float* __restrict__ bnsum, float* __restrict__ bnsq)
{
  __shared__ float ss[256], sq[256];
  int t = threadIdx.x;
  int c = t & 127, hh = t >> 7;
  float s = 0.f, q = 0.f;
  for (int n = blockIdx.x * 2 + hh; n < Nn; n += gridDim.x * 2) {
    float v = A[(size_t)n * HC + c];
    s += v; q += v * v;
  }
  ss[t] = s; sq[t] = q;
  __syncthreads();
  if (t < 128) {
    atomicAdd(&bnsum[c], ss[t] + ss[t+128]);
    atomicAdd(&bnsq[c],  sq[t] + sq[t+128]);
  }
}

// global mean pool with BN+ReLU of final layer fused
__global__ void pool_kernel(const float* __restrict__ A, const int* __restrict__ batch,
                            const float* __restrict__ bnsum, const float* __restrict__ bnsq,
                            const float* __restrict__ gammaL, const float* __restrict__ betaL,
                            float* __restrict__ pool)
{
  int t = threadIdx.x;
  int c = t & 127, hh = t >> 7;
  float mu  = bnsum[c] * (1.f / Nn);
  float var = bnsq[c] * (1.f / Nn) - mu * mu;
  float s_ = rsqrtf(var + BN_EPS) * gammaL[c];
  float sh_ = betaL[c] - mu * s_;
  int n0 = blockIdx.x * 256;
  float accv = 0.f; int curg = -1;
  for (int i = hh; i < 256; i += 2) {
    int n = n0 + i;
    if (n >= Nn) break;
    int g = batch[n];
    if (g != curg) {
      if (curg >= 0) atomicAdd(&pool[(size_t)curg * HC + c], accv);
      curg = g; accv = 0.f;
    }
    accv += fmaxf(A[(size_t)n * HC + c] * s_ + sh_, 0.f);
  }
  if (curg >= 0) atomicAdd(&pool[(size_t)curg * HC + c], accv);
}

__device__ __forceinline__ int lbound(const int* __restrict__ a, int n, int key)
{
  int lo = 0, hi = n;
  while (lo < hi) {
    int mid = (lo + hi) >> 1;
    if (a[mid] < key) lo = mid + 1; else hi = mid;
  }
  return lo;
}

__global__ void final_fc(const float* __restrict__ pool, const int* __restrict__ batch,
                         const float* __restrict__ fcW, const float* __restrict__ fcb,
                         float* __restrict__ out)
{
  int t = blockIdx.x * 256 + threadIdx.x;
  if (t >= Gg * NOUT) return;
  int g = t >> 1, o = t & 1;
  int lo = lbound(batch, Nn, g);
  int hi = lbound(batch, Nn, g + 1);
  float cn = fmaxf((float)(hi - lo), 1.f);
  float acc = 0.f;
  for (int k = 0; k < HC; ++k)
    acc += pool[(size_t)g * HC + k] * fcW[k * NOUT + o];
  out[t] = acc / cn + fcb[o];
}

extern "C" void kernel_launch(void* const* d_in, const int* in_sizes, int n_in,
                              void* d_out, int out_size, void* d_ws, size_t ws_size,
                              hipStream_t stream)
{
  const float* x      = (const float*)d_in[0];
  const int*   eidx   = (const int*)d_in[1];
  const float* eattr  = (const float*)d_in[2];
  const int*   batch  = (const int*)d_in[3];
  const float* efcW   = (const float*)d_in[4];
  const float* efcb   = (const float*)d_in[5];
  const float* Wall   = (const float*)d_in[6];
  const float* attS   = (const float*)d_in[7];
  const float* attD   = (const float*)d_in[8];
  const float* attE   = (const float*)d_in[9];
  const float* linE   = (const float*)d_in[10];
  const float* biases = (const float*)d_in[11];
  const float* gamma  = (const float*)d_in[12];
  const float* beta   = (const float*)d_in[13];
  const float* fcW    = (const float*)d_in[14];
  const float* fcb    = (const float*)d_in[15];
  float* out = (float*)d_out;

  const int* src = eidx;
  const int* dst = eidx + Ee;

  float* ws    = (float*)d_ws;
  float* bufA  = ws;                            // N*128 (f32 or packed u32)
  float* bufB  = bufA + (size_t)Nn*HC;          // N*128
  float* as_   = bufB + (size_t)Nn*HC;          // N*4
  float* ad_   = as_ + (size_t)Nn*NHD;          // N*4
  float* ew_s  = ad_ + (size_t)Nn*NHD;          // E*4 (16B aligned)
  float* Kmat  = ew_s + (size_t)Ee*NHD;         // 192
  float* kb    = Kmat + 192;                    // 16
  float* bnsum = kb + 16;                       // 128
  float* bnsq  = bnsum + 128;                   // 128
  float* pool  = bnsq + 128;                    // G*128
  int*   rowp  = (int*)(pool + (size_t)Gg*HC);  // N+1
  int*   deg   = rowp + (Nn + 1);               // N
  int*   fill  = deg + Nn;                      // N  (deg..fill one memset)
  int*   src_s = fill + Nn;                     // E
  int*   perm  = src_s + Ee;                    // E
  int*   bsum  = perm + Ee;                     // NSB
  int*   bpre  = bsum + 128;                    // NSB
  u32*   Wf    = (u32*)(bpre + 128);            // 3*128*128 u32 (192 KB)

  w_split<<<(3*HC*HC + 255)/256, 256, 0, stream>>>(Wall, Wf);
  compute_K<<<1, 512, 0, stream>>>(efcW, efcb, linE, attE, Kmat, kb);

  // CSR build (reused across all 3 layers)
  hipMemsetAsync(deg, 0, 2*Nn*sizeof(int), stream);
  k_hist<<<(Ee + 255)/256, 256, 0, stream>>>(dst, deg);
  k_bsum<<<NSB, 256, 0, stream>>>(deg, bsum);
  k_mid<<<1, 128, 0, stream>>>(bsum, bpre, rowp);
  k_scan<<<NSB, 256, 0, stream>>>(deg, bpre, rowp);
  k_fill<<<(Ee + 255)/256, 256, 0, stream>>>(src, dst, rowp, fill, src_s, perm);

  for (int l = 0; l < 3; ++l) {
    // split prev activations (x for l=0; BN+ReLU for l>0) into packed bf16 hi/lo, in-place for l>0
    if (l == 0)
      split_bn<<<(Nn*HC/4 + 255)/256, 256, 0, stream>>>(x, (u32*)bufA, nullptr, nullptr, nullptr, nullptr, 0);
    else
      split_bn<<<(Nn*HC/4 + 255)/256, 256, 0, stream>>>(bufA, (u32*)bufA, bnsum, bnsq,
                                                        gamma + (l-1)*HC, beta + (l-1)*HC, 1);
    gemm_mfma<<<(Nn + 127)/128, 256, 0, stream>>>((const u32*)bufA, Wf + (size_t)l*HC*HC, bufB,
                                                  attS + l*HC, attD + l*HC, as_, ad_);
    edge_alpha<<<(Ee + 255)/256, 256, 0, stream>>>(src, dst, eattr, Kmat, kb, l, as_, ad_, perm, ew_s);
    aggregate<<<(Nn + 7)/8, 256, 0, stream>>>(rowp, src_s, ew_s, bufB, biases + l*HC, bufA);
    hipMemsetAsync(bnsum, 0, 256*sizeof(float), stream);
    bn_reduce<<<1024, 256, 0, stream>>>(bufA, bnsum, bnsq);
  }

  hipMemsetAsync(pool, 0, (size_t)Gg*HC*sizeof(float), stream);
  pool_kernel<<<(Nn + 255)/256, 256, 0, stream>>>(bufA, batch, bnsum, bnsq, gamma + 2*HC, beta + 2*HC, pool);
  final_fc<<<2, 256, 0, stream>>>(pool, batch, fcW, fcb, out);
}

// Round 11
// 813.445 us; speedup vs baseline: 1.1963x; 1.1410x over previous
//
#include <hip/hip_runtime.h>

#define Nn 100000
#define Ee 800000
#define HC 128
#define HID 32
#define NHD 4
#define EDIM 16
#define Gg 256
#define NOUT 2
#define SLOPE 0.2f
#define BN_EPS 1e-5f
#define SCHUNK 1024
#define NSB 98   // ceil(Nn/SCHUNK)

typedef unsigned int u32;
typedef unsigned short u16;
typedef short v8s __attribute__((ext_vector_type(8)));
typedef float v4f __attribute__((ext_vector_type(4)));

union PkAB { u32 u[4]; v8s v; };

__device__ __forceinline__ float bflo(u32 u){ return __uint_as_float(u << 16); }
__device__ __forceinline__ float bfhi(u32 u){ return __uint_as_float(u & 0xFFFF0000u); }

// round-to-nearest-even f32 -> bf16 bits
__device__ __forceinline__ u32 bf16rne(float x)
{
  u32 b = __float_as_uint(x);
  return (b + 0x7FFFu + ((b >> 16) & 1u)) >> 16;
}
// pack x into (hi bf16 | lo bf16 << 16)
__device__ __forceinline__ u32 packsplit(float x)
{
  u32 hb = bf16rne(x);
  float hf = __uint_as_float(hb << 16);
  u32 lb = bf16rne(x - hf);
  return hb | (lb << 16);
}

// ---- tiny weight precompute: Kmat[16][12], kb[12]  (edge-path algebraic fold) ----
__global__ void compute_K(const float* __restrict__ efcW, const float* __restrict__ efcb,
                          const float* __restrict__ linE, const float* __restrict__ attE,
                          float* __restrict__ Kmat, float* __restrict__ kb)
{
  __shared__ float Msh[384];
  int t = threadIdx.x;
  if (t < 384) {
    int l = t >> 7, j = (t >> 2) & 31, h = t & 3;
    float m = 0.f;
    for (int c = 0; c < 32; ++c)
      m += linE[(l*32 + j)*128 + h*32 + c] * attE[(l*4 + h)*32 + c];
    Msh[l*128 + j*4 + h] = m;
  }
  __syncthreads();
  if (t < 192) {
    int k = t / 12, col = t % 12, l = col >> 2, h = col & 3;
    float acc = 0.f;
    for (int j = 0; j < 32; ++j)
      acc += efcW[k*32 + j] * Msh[l*128 + j*4 + h];
    Kmat[k*12 + col] = acc;
  } else if (t < 204) {
    int col = t - 192, l = col >> 2, h = col & 3;
    float acc = 0.f;
    for (int j = 0; j < 32; ++j)
      acc += efcb[j] * Msh[l*128 + j*4 + h];
    kb[col] = acc;
  }
}

// ---- W -> split-bf16 MFMA B-fragment layout (once) ----
__global__ void w_split(const float* __restrict__ Wall, u32* __restrict__ Wf)
{
  int tid = blockIdx.x * 256 + threadIdx.x;
  if (tid >= 3*HC*HC) return;
  int l = tid / (HC*HC);
  int rem = tid - l*HC*HC;
  int k = rem >> 7, n = rem & 127;
  u32 p = packsplit(Wall[tid]);
  int nt = n >> 4, col = n & 15;
  int ks = k >> 5, kin = k & 31, q = kin >> 3, j = kin & 7;
  int half = j >> 2, j4 = j & 3;
  int idx = ((((l*8 + nt)*4 + ks)*2 + half)*64 + q*16 + col)*4 + j4;
  Wf[idx] = p;
}

// ---- CSR build ----
__global__ void k_hist(const int* __restrict__ dst, int* __restrict__ deg)
{
  int e = blockIdx.x * 256 + threadIdx.x;
  if (e < Ee) atomicAdd(&deg[dst[e]], 1);
}

__global__ void k_bsum(const int* __restrict__ deg, int* __restrict__ bsum)
{
  __shared__ int sh[256];
  int b = blockIdx.x, t = threadIdx.x;
  int s = 0;
  for (int i = t; i < SCHUNK; i += 256) {
    int idx = b*SCHUNK + i;
    if (idx < Nn) s += deg[idx];
  }
  sh[t] = s; __syncthreads();
  for (int o = 128; o; o >>= 1) { if (t < o) sh[t] += sh[t+o]; __syncthreads(); }
  if (!t) bsum[b] = sh[0];
}

__global__ void k_mid(const int* __restrict__ bsum, int* __restrict__ bpre, int* __restrict__ rowp)
{
  __shared__ int sh[NSB];
  int t = threadIdx.x;
  if (t < NSB) sh[t] = bsum[t];
  __syncthreads();
  if (!t) {
    int run = 0;
    for (int i = 0; i < NSB; ++i) { int v = sh[i]; sh[i] = run; run += v; }
    rowp[Nn] = run;
  }
  __syncthreads();
  if (t < NSB) bpre[t] = sh[t];
}

__global__ void k_scan(const int* __restrict__ deg, const int* __restrict__ bpre, int* __restrict__ rowp)
{
  __shared__ int sh[SCHUNK];
  int b = blockIdx.x, t = threadIdx.x;
  for (int i = t; i < SCHUNK; i += 256) {
    int idx = b*SCHUNK + i;
    sh[i] = (idx < Nn) ? deg[idx] : 0;
  }
  __syncthreads();
  if (!t) {
    int run = 0;
    for (int i = 0; i < SCHUNK; ++i) { int v = sh[i]; sh[i] = run; run += v; }
  }
  __syncthreads();
  int base = bpre[b];
  for (int i = t; i < SCHUNK; i += 256) {
    int idx = b*SCHUNK + i;
    if (idx < Nn) rowp[idx] = sh[i] + base;
  }
}

__global__ void k_fill(const int* __restrict__ src, const int* __restrict__ dst,
                       const int* __restrict__ rowp, int* __restrict__ fill,
                       int* __restrict__ src_s, int* __restrict__ perm)
{
  int e = blockIdx.x * 256 + threadIdx.x;
  if (e >= Ee) return;
  int d = dst[e];
  int pos = rowp[d] + atomicAdd(&fill[d], 1);
  src_s[pos] = src[e];
  perm[e] = pos;
}

__device__ __forceinline__ int lbound(const int* __restrict__ a, int n, int key)
{
  int lo = 0, hi = n;
  while (lo < hi) {
    int mid = (lo + hi) >> 1;
    if (a[mid] < key) lo = mid + 1; else hi = mid;
  }
  return lo;
}

// per-graph node bounds (batch sorted)
__global__ void k_gb(const int* __restrict__ batch, int* __restrict__ gb)
{
  int g = blockIdx.x * 256 + threadIdx.x;
  if (g <= Gg) gb[g] = lbound(batch, Nn, g);
}

// ---- BN(+ReLU) of prev layer + split-pack to bf16 hi/lo, in-place safe ----
__global__ void split_bn(const float* src, u32* dst,
                         const float* __restrict__ bnsum, const float* __restrict__ bnsq,
                         const float* __restrict__ gammaL, const float* __restrict__ betaL,
                         int apply_bn)
{
  int idx = blockIdx.x * 256 + threadIdx.x;
  if (idx >= Nn*HC/4) return;
  float4 v = ((const float4*)src)[idx];
  if (apply_bn) {
    int c = (idx * 4) & 127;
    float s0, t0, s1, t1, s2, t2, s3, t3;
    {
      float mu  = bnsum[c+0] * (1.f/Nn); float var = bnsq[c+0] * (1.f/Nn) - mu*mu;
      s0 = rsqrtf(var + BN_EPS) * gammaL[c+0]; t0 = betaL[c+0] - mu * s0;
    }
    {
      float mu  = bnsum[c+1] * (1.f/Nn); float var = bnsq[c+1] * (1.f/Nn) - mu*mu;
      s1 = rsqrtf(var + BN_EPS) * gammaL[c+1]; t1 = betaL[c+1] - mu * s1;
    }
    {
      float mu  = bnsum[c+2] * (1.f/Nn); float var = bnsq[c+2] * (1.f/Nn) - mu*mu;
      s2 = rsqrtf(var + BN_EPS) * gammaL[c+2]; t2 = betaL[c+2] - mu * s2;
    }
    {
      float mu  = bnsum[c+3] * (1.f/Nn); float var = bnsq[c+3] * (1.f/Nn) - mu*mu;
      s3 = rsqrtf(var + BN_EPS) * gammaL[c+3]; t3 = betaL[c+3] - mu * s3;
    }
    v.x = fmaxf(v.x*s0 + t0, 0.f);
    v.y = fmaxf(v.y*s1 + t1, 0.f);
    v.z = fmaxf(v.z*s2 + t2, 0.f);
    v.w = fmaxf(v.w*s3 + t3, 0.f);
  }
  uint4 o;
  o.x = packsplit(v.x); o.y = packsplit(v.y);
  o.z = packsplit(v.z); o.w = packsplit(v.w);
  ((uint4*)dst)[idx] = o;
}

// ---- MFMA GEMM; C output as rne-bf16 (u16 per channel); attn dots fused (f32 acc)
__global__ __launch_bounds__(256, 2) void gemm_mfma(const u32* __restrict__ Apk,
                                                    const u32* __restrict__ Wf,
                                                    u16* __restrict__ C2,
                                                    const float* __restrict__ aS,
                                                    const float* __restrict__ aD,
                                                    float* __restrict__ as_,
                                                    float* __restrict__ ad_)
{
  int t = threadIdx.x;
  int w = t >> 6, lane = t & 63;
  int col = lane & 15, q = lane >> 4;
  int rbase = blockIdx.x * 128 + w * 32;

  v4f acc[2][8];
  #pragma unroll
  for (int mt = 0; mt < 2; ++mt)
    #pragma unroll
    for (int nt = 0; nt < 8; ++nt)
      acc[mt][nt] = (v4f){0.f, 0.f, 0.f, 0.f};

  const uint4* Wf4 = (const uint4*)Wf;

  for (int ks = 0; ks < 4; ++ks) {
    PkAB Ah[2], Al[2];
    #pragma unroll
    for (int mt = 0; mt < 2; ++mt) {
      int ar = rbase + mt*16 + col;
      if (ar >= Nn) ar = Nn - 1;
      const uint4* pa = (const uint4*)(Apk + (size_t)ar*HC + ks*32 + q*8);
      uint4 r0 = pa[0], r1 = pa[1];
      Ah[mt].u[0] = (r0.x & 0xFFFFu) | (r0.y << 16);
      Al[mt].u[0] = (r0.x >> 16)     | (r0.y & 0xFFFF0000u);
      Ah[mt].u[1] = (r0.z & 0xFFFFu) | (r0.w << 16);
      Al[mt].u[1] = (r0.z >> 16)     | (r0.w & 0xFFFF0000u);
      Ah[mt].u[2] = (r1.x & 0xFFFFu) | (r1.y << 16);
      Al[mt].u[2] = (r1.x >> 16)     | (r1.y & 0xFFFF0000u);
      Ah[mt].u[3] = (r1.z & 0xFFFFu) | (r1.w << 16);
      Al[mt].u[3] = (r1.z >> 16)     | (r1.w & 0xFFFF0000u);
    }
    #pragma unroll
    for (int nt = 0; nt < 8; ++nt) {
      uint4 b0 = Wf4[((nt*4 + ks)*2 + 0)*64 + lane];
      uint4 b1 = Wf4[((nt*4 + ks)*2 + 1)*64 + lane];
      PkAB Bh, Bl;
      Bh.u[0] = (b0.x & 0xFFFFu) | (b0.y << 16);
      Bl.u[0] = (b0.x >> 16)     | (b0.y & 0xFFFF0000u);
      Bh.u[1] = (b0.z & 0xFFFFu) | (b0.w << 16);
      Bl.u[1] = (b0.z >> 16)     | (b0.w & 0xFFFF0000u);
      Bh.u[2] = (b1.x & 0xFFFFu) | (b1.y << 16);
      Bl.u[2] = (b1.x >> 16)     | (b1.y & 0xFFFF0000u);
      Bh.u[3] = (b1.z & 0xFFFFu) | (b1.w << 16);
      Bl.u[3] = (b1.z >> 16)     | (b1.w & 0xFFFF0000u);
      #pragma unroll
      for (int mt = 0; mt < 2; ++mt) {
        acc[mt][nt] = __builtin_amdgcn_mfma_f32_16x16x32_bf16(Ah[mt].v, Bh.v, acc[mt][nt], 0, 0, 0);
        acc[mt][nt] = __builtin_amdgcn_mfma_f32_16x16x32_bf16(Ah[mt].v, Bl.v, acc[mt][nt], 0, 0, 0);
        acc[mt][nt] = __builtin_amdgcn_mfma_f32_16x16x32_bf16(Al[mt].v, Bh.v, acc[mt][nt], 0, 0, 0);
      }
    }
  }

  // C store (bf16): row = rbase + mt*16 + q*4 + reg, col = nt*16 + (lane&15)
  #pragma unroll
  for (int mt = 0; mt < 2; ++mt) {
    #pragma unroll
    for (int reg = 0; reg < 4; ++reg) {
      int row = rbase + mt*16 + q*4 + reg;
      if (row < Nn) {
        #pragma unroll
        for (int nt = 0; nt < 8; ++nt)
          C2[(size_t)row*HC + nt*16 + col] = (u16)bf16rne(acc[mt][nt][reg]);
      }
    }
  }

  // fused attn dots (f32 accumulators)
  #pragma unroll
  for (int mt = 0; mt < 2; ++mt) {
    #pragma unroll
    for (int h = 0; h < 4; ++h) {
      float a0 = aS[32*h + col], a1 = aS[32*h + 16 + col];
      float d0 = aD[32*h + col], d1 = aD[32*h + 16 + col];
      #pragma unroll
      for (int reg = 0; reg < 4; ++reg) {
        float s1 = acc[mt][2*h][reg]*a0 + acc[mt][2*h+1][reg]*a1;
        float s2 = acc[mt][2*h][reg]*d0 + acc[mt][2*h+1][reg]*d1;
        s1 += __shfl_xor(s1, 1); s1 += __shfl_xor(s1, 2);
        s1 += __shfl_xor(s1, 4); s1 += __shfl_xor(s1, 8);
        s2 += __shfl_xor(s2, 1); s2 += __shfl_xor(s2, 2);
        s2 += __shfl_xor(s2, 4); s2 += __shfl_xor(s2, 8);
        if (col == 0) {
          int row = rbase + mt*16 + q*4 + reg;
          if (row < Nn) {
            as_[row*NHD + h] = s1;
            ad_[row*NHD + h] = s2;
          }
        }
      }
    }
  }
}

// alpha -> leaky -> w=exp(alpha), scattered into dst-sorted position
__global__ void edge_alpha(const int* __restrict__ src, const int* __restrict__ dst,
                           const float* __restrict__ eattr, const float* __restrict__ Kmat,
                           const float* __restrict__ kb, int l,
                           const float* __restrict__ as_, const float* __restrict__ ad_,
                           const int* __restrict__ perm, float* __restrict__ ew_s)
{
  int e = blockIdx.x * 256 + threadIdx.x;
  if (e >= Ee) return;
  const float4* p = (const float4*)(eattr + (size_t)e * EDIM);
  float ea[16];
  #pragma unroll
  for (int qq = 0; qq < 4; ++qq) {
    float4 v = p[qq];
    ea[qq*4+0] = v.x; ea[qq*4+1] = v.y; ea[qq*4+2] = v.z; ea[qq*4+3] = v.w;
  }
  float al[4];
  #pragma unroll
  for (int h = 0; h < 4; ++h) al[h] = kb[l*4 + h];
  #pragma unroll
  for (int k = 0; k < 16; ++k) {
    float v = ea[k];
    #pragma unroll
    for (int h = 0; h < 4; ++h) al[h] += v * Kmat[k*12 + l*4 + h];
  }
  int s = src[e], d = dst[e];
  float4 sv = *(const float4*)(as_ + (size_t)s * 4);
  float4 dv = *(const float4*)(ad_ + (size_t)d * 4);
  float4 a;
  a.x = al[0] + sv.x + dv.x; a.y = al[1] + sv.y + dv.y;
  a.z = al[2] + sv.z + dv.z; a.w = al[3] + sv.w + dv.w;
  a.x = (a.x > 0.f) ? a.x : SLOPE * a.x;
  a.y = (a.y > 0.f) ? a.y : SLOPE * a.y;
  a.z = (a.z > 0.f) ? a.z : SLOPE * a.z;
  a.w = (a.w > 0.f) ? a.w : SLOPE * a.w;
  float4 w;
  w.x = __expf(a.x); w.y = __expf(a.y); w.z = __expf(a.z); w.w = __expf(a.w);
  int pos = perm[e];
  *(float4*)(ew_s + (size_t)pos * 4) = w;
}

// CSR aggregation over bf16-packed xl rows (256 B/row): 32 thr/node, uint2/thread
__global__ __launch_bounds__(256) void aggregate(const int* __restrict__ rowp, const int* __restrict__ src_s,
                                                 const float* __restrict__ ew_s, const u32* __restrict__ xl2,
                                                 const float* __restrict__ bias, float* __restrict__ outp)
{
  int n = blockIdx.x * 8 + (threadIdx.x >> 5);
  if (n >= Nn) return;
  int c4 = threadIdx.x & 31;        // channels c4*4 .. c4*4+3
  int h = c4 >> 3;
  int beg = rowp[n], end = rowp[n+1];
  float4 acc = make_float4(0.f,0.f,0.f,0.f);
  float wsum = 0.f;
  int i = beg;
  for (; i + 8 <= end; i += 8) {
    int s[8]; float w[8]; uint2 v[8];
    #pragma unroll
    for (int j = 0; j < 8; ++j) s[j] = src_s[i+j];
    #pragma unroll
    for (int j = 0; j < 8; ++j) w[j] = ew_s[(size_t)(i+j)*4 + h];
    #pragma unroll
    for (int j = 0; j < 8; ++j) v[j] = *(const uint2*)(xl2 + (size_t)s[j] * 64 + c4*2);
    #pragma unroll
    for (int j = 0; j < 8; ++j) {
      acc.x += w[j]*bflo(v[j].x); acc.y += w[j]*bfhi(v[j].x);
      acc.z += w[j]*bflo(v[j].y); acc.w += w[j]*bfhi(v[j].y);
      wsum += w[j];
    }
  }
  for (; i < end; ++i) {
    int s = src_s[i];
    float w = ew_s[(size_t)i*4 + h];
    uint2 v = *(const uint2*)(xl2 + (size_t)s * 64 + c4*2);
    acc.x += w*bflo(v.x); acc.y += w*bfhi(v.x);
    acc.z += w*bflo(v.y); acc.w += w*bfhi(v.y);
    wsum += w;
  }
  float inv = 1.f / (wsum + 1e-16f);
  float4 b4 = *(const float4*)(bias + c4*4);
  float4 o;
  o.x = acc.x*inv + b4.x; o.y = acc.y*inv + b4.y;
  o.z = acc.z*inv + b4.z; o.w = acc.w*inv + b4.w;
  *(float4*)(outp + (size_t)n * HC + c4*4) = o;
}

__global__ void bn_reduce(const float* __restrict__ A, float* __restrict__ bnsum, float* __restrict__ bnsq)
{
  __shared__ float ss[256], sq[256];
  int t = threadIdx.x;
  int c = t & 127, hh = t >> 7;
  float s = 0.f, q = 0.f;
  for (int n = blockIdx.x * 2 + hh; n < Nn; n += gridDim.x * 2) {
    float v = A[(size_t)n * HC + c];
    s += v; q += v * v;
  }
  ss[t] = s; sq[t] = q;
  __syncthreads();
  if (t < 128) {
    atomicAdd(&bnsum[c], ss[t] + ss[t+128]);
    atomicAdd(&bnsq[c],  sq[t] + sq[t+128]);
  }
}

// mean-pool with final-layer BN+ReLU fused; per (graph x channel-quarter) block; no atomics
__global__ __launch_bounds__(256) void pool2(const float* __restrict__ A, const int* __restrict__ gb,
                                             const float* __restrict__ bnsum, const float* __restrict__ bnsq,
                                             const float* __restrict__ gammaL, const float* __restrict__ betaL,
                                             float* __restrict__ pool)
{
  __shared__ float4 red[256];
  int g = blockIdx.x >> 2, qt = blockIdx.x & 3;
  int t = threadIdx.x;
  int cg = t & 7;                 // float4 group within quarter
  int rs = t >> 3;                // 0..31 node stride
  int c4 = qt*8 + cg;             // global float4 group (channels c4*4..+3)
  int c = c4 * 4;
  int lo = gb[g], hi = gb[g+1];
  float s0, t0, s1, t1, s2, t2, s3, t3;
  {
    float mu = bnsum[c+0]*(1.f/Nn); float var = bnsq[c+0]*(1.f/Nn) - mu*mu;
    s0 = rsqrtf(var + BN_EPS) * gammaL[c+0]; t0 = betaL[c+0] - mu*s0;
  }
  {
    float mu = bnsum[c+1]*(1.f/Nn); float var = bnsq[c+1]*(1.f/Nn) - mu*mu;
    s1 = rsqrtf(var + BN_EPS) * gammaL[c+1]; t1 = betaL[c+1] - mu*s1;
  }
  {
    float mu = bnsum[c+2]*(1.f/Nn); float var = bnsq[c+2]*(1.f/Nn) - mu*mu;
    s2 = rsqrtf(var + BN_EPS) * gammaL[c+2]; t2 = betaL[c+2] - mu*s2;
  }
  {
    float mu = bnsum[c+3]*(1.f/Nn); float var = bnsq[c+3]*(1.f/Nn) - mu*mu;
    s3 = rsqrtf(var + BN_EPS) * gammaL[c+3]; t3 = betaL[c+3] - mu*s3;
  }
  float4 acc = make_float4(0.f,0.f,0.f,0.f);
  for (int n = lo + rs; n < hi; n += 32) {
    float4 v = *(const float4*)(A + (size_t)n*HC + c);
    acc.x += fmaxf(v.x*s0 + t0, 0.f);
    acc.y += fmaxf(v.y*s1 + t1, 0.f);
    acc.z += fmaxf(v.z*s2 + t2, 0.f);
    acc.w += fmaxf(v.w*s3 + t3, 0.f);
  }
  red[t] = acc;
  __syncthreads();
  for (int off = 128; off >= 8; off >>= 1) {
    if (t < off) {
      red[t].x += red[t+off].x; red[t].y += red[t+off].y;
      red[t].z += red[t+off].z; red[t].w += red[t+off].w;
    }
    __syncthreads();
  }
  if (t < 8) {
    float inv = 1.f / fmaxf((float)(hi - lo), 1.f);
    float4 r = red[t];
    r.x *= inv; r.y *= inv; r.z *= inv; r.w *= inv;
    *(float4*)(pool + (size_t)g*HC + qt*32 + t*4) = r;
  }
}

__global__ void final_fc(const float* __restrict__ pool,
                         const float* __restrict__ fcW, const float* __restrict__ fcb,
                         float* __restrict__ out)
{
  int t = blockIdx.x * 256 + threadIdx.x;
  if (t >= Gg * NOUT) return;
  int g = t >> 1, o = t & 1;
  float acc = 0.f;
  for (int k = 0; k < HC; ++k)
    acc += pool[(size_t)g * HC + k] * fcW[k * NOUT + o];
  out[t] = acc + fcb[o];
}

extern "C" void kernel_launch(void* const* d_in, const int* in_sizes, int n_in,
                              void* d_out, int out_size, void* d_ws, size_t ws_size,
                              hipStream_t stream)
{
  const float* x      = (const float*)d_in[0];
  const int*   eidx   = (const int*)d_in[1];
  const float* eattr  = (const float*)d_in[2];
  const int*   batch  = (const int*)d_in[3];
  const float* efcW   = (const float*)d_in[4];
  const float* efcb   = (const float*)d_in[5];
  const float* Wall   = (const float*)d_in[6];
  const float* attS   = (const float*)d_in[7];
  const float* attD   = (const float*)d_in[8];
  const float* attE   = (const float*)d_in[9];
  const float* linE   = (const float*)d_in[10];
  const float* biases = (const float*)d_in[11];
  const float* gamma  = (const float*)d_in[12];
  const float* beta   = (const float*)d_in[13];
  const float* fcW    = (const float*)d_in[14];
  const float* fcb    = (const float*)d_in[15];
  float* out = (float*)d_out;

  const int* src = eidx;
  const int* dst = eidx + Ee;

  float* ws    = (float*)d_ws;
  float* bufA  = ws;                            // N*128 (f32 / packed u32)
  float* bufB  = bufA + (size_t)Nn*HC;          // N*128 (u16 bf16 rows use half)
  float* as_   = bufB + (size_t)Nn*HC;          // N*4
  float* ad_   = as_ + (size_t)Nn*NHD;          // N*4
  float* ew_s  = ad_ + (size_t)Nn*NHD;          // E*4
  float* Kmat  = ew_s + (size_t)Ee*NHD;         // 192
  float* kb    = Kmat + 192;                    // 16
  float* bnsum = kb + 16;                       // 128
  float* bnsq  = bnsum + 128;                   // 128
  float* pool  = bnsq + 128;                    // G*128
  int*   rowp  = (int*)(pool + (size_t)Gg*HC);  // N+1
  int*   deg   = rowp + (Nn + 1);               // N
  int*   fill  = deg + Nn;                      // N
  int*   src_s = fill + Nn;                     // E
  int*   perm  = src_s + Ee;                    // E
  int*   bsum  = perm + Ee;                     // NSB
  int*   bpre  = bsum + 128;                    // NSB
  u32*   Wf    = (u32*)(bpre + 128);            // 3*128*128 u32
  int*   gb    = (int*)(Wf + 3*HC*HC);          // Gg+1

  w_split<<<(3*HC*HC + 255)/256, 256, 0, stream>>>(Wall, Wf);
  compute_K<<<1, 512, 0, stream>>>(efcW, efcb, linE, attE, Kmat, kb);
  k_gb<<<2, 256, 0, stream>>>(batch, gb);

  // CSR build (reused across all 3 layers)
  hipMemsetAsync(deg, 0, 2*Nn*sizeof(int), stream);
  k_hist<<<(Ee + 255)/256, 256, 0, stream>>>(dst, deg);
  k_bsum<<<NSB, 256, 0, stream>>>(deg, bsum);
  k_mid<<<1, 128, 0, stream>>>(bsum, bpre, rowp);
  k_scan<<<NSB, 256, 0, stream>>>(deg, bpre, rowp);
  k_fill<<<(Ee + 255)/256, 256, 0, stream>>>(src, dst, rowp, fill, src_s, perm);

  for (int l = 0; l < 3; ++l) {
    if (l == 0)
      split_bn<<<(Nn*HC/4 + 255)/256, 256, 0, stream>>>(x, (u32*)bufA, nullptr, nullptr, nullptr, nullptr, 0);
    else
      split_bn<<<(Nn*HC/4 + 255)/256, 256, 0, stream>>>(bufA, (u32*)bufA, bnsum, bnsq,
                                                        gamma + (l-1)*HC, beta + (l-1)*HC, 1);
    gemm_mfma<<<(Nn + 127)/128, 256, 0, stream>>>((const u32*)bufA, Wf + (size_t)l*HC*HC, (u16*)bufB,
                                                  attS + l*HC, attD + l*HC, as_, ad_);
    edge_alpha<<<(Ee + 255)/256, 256, 0, stream>>>(src, dst, eattr, Kmat, kb, l, as_, ad_, perm, ew_s);
    aggregate<<<(Nn + 7)/8, 256, 0, stream>>>(rowp, src_s, ew_s, (const u32*)bufB, biases + l*HC, bufA);
    hipMemsetAsync(bnsum, 0, 256*sizeof(float), stream);
    bn_reduce<<<1024, 256, 0, stream>>>(bufA, bnsum, bnsq);
  }

  pool2<<<Gg*4, 256, 0, stream>>>(bufA, gb, bnsum, bnsq, gamma + 2*HC, beta + 2*HC, pool);
  final_fc<<<2, 256, 0, stream>>>(pool, fcW, fcb, out);
}

// Round 12
// 797.605 us; speedup vs baseline: 1.2201x; 1.0199x over previous
//
#include <hip/hip_runtime.h>

#define Nn 100000
#define Ee 800000
#define HC 128
#define HID 32
#define NHD 4
#define EDIM 16
#define Gg 256
#define NOUT 2
#define SLOPE 0.2f
#define BN_EPS 1e-5f
#define SCHUNK 1024
#define NSB 98   // ceil(Nn/SCHUNK)

typedef unsigned int u32;
typedef unsigned short u16;
typedef short v8s __attribute__((ext_vector_type(8)));
typedef float v4f __attribute__((ext_vector_type(4)));

union PkAB { u32 u[4]; v8s v; };

__device__ __forceinline__ float bflo(u32 u){ return __uint_as_float(u << 16); }
__device__ __forceinline__ float bfhi(u32 u){ return __uint_as_float(u & 0xFFFF0000u); }

__device__ __forceinline__ u32 bf16rne(float x)
{
  u32 b = __float_as_uint(x);
  return (b + 0x7FFFu + ((b >> 16) & 1u)) >> 16;
}
__device__ __forceinline__ u32 packsplit(float x)
{
  u32 hb = bf16rne(x);
  float hf = __uint_as_float(hb << 16);
  u32 lb = bf16rne(x - hf);
  return hb | (lb << 16);
}

// ---- tiny weight precompute: Kmat[16][12], kb[12] ----
__global__ void compute_K(const float* __restrict__ efcW, const float* __restrict__ efcb,
                          const float* __restrict__ linE, const float* __restrict__ attE,
                          float* __restrict__ Kmat, float* __restrict__ kb)
{
  __shared__ float Msh[384];
  int t = threadIdx.x;
  if (t < 384) {
    int l = t >> 7, j = (t >> 2) & 31, h = t & 3;
    float m = 0.f;
    for (int c = 0; c < 32; ++c)
      m += linE[(l*32 + j)*128 + h*32 + c] * attE[(l*4 + h)*32 + c];
    Msh[l*128 + j*4 + h] = m;
  }
  __syncthreads();
  if (t < 192) {
    int k = t / 12, col = t % 12, l = col >> 2, h = col & 3;
    float acc = 0.f;
    for (int j = 0; j < 32; ++j)
      acc += efcW[k*32 + j] * Msh[l*128 + j*4 + h];
    Kmat[k*12 + col] = acc;
  } else if (t < 204) {
    int col = t - 192, l = col >> 2, h = col & 3;
    float acc = 0.f;
    for (int j = 0; j < 32; ++j)
      acc += efcb[j] * Msh[l*128 + j*4 + h];
    kb[col] = acc;
  }
}

// ---- W -> split-bf16 MFMA B-fragment layout (once) ----
__global__ void w_split(const float* __restrict__ Wall, u32* __restrict__ Wf)
{
  int tid = blockIdx.x * 256 + threadIdx.x;
  if (tid >= 3*HC*HC) return;
  int l = tid / (HC*HC);
  int rem = tid - l*HC*HC;
  int k = rem >> 7, n = rem & 127;
  u32 p = packsplit(Wall[tid]);
  int nt = n >> 4, col = n & 15;
  int ks = k >> 5, kin = k & 31, q = kin >> 3, j = kin & 7;
  int half = j >> 2, j4 = j & 3;
  int idx = ((((l*8 + nt)*4 + ks)*2 + half)*64 + q*16 + col)*4 + j4;
  Wf[idx] = p;
}

// ---- CSR build ----
__global__ void k_hist(const int* __restrict__ dst, int* __restrict__ deg)
{
  int e = blockIdx.x * 256 + threadIdx.x;
  if (e < Ee) atomicAdd(&deg[dst[e]], 1);
}

__global__ void k_bsum(const int* __restrict__ deg, int* __restrict__ bsum)
{
  __shared__ int sh[256];
  int b = blockIdx.x, t = threadIdx.x;
  int s = 0;
  for (int i = t; i < SCHUNK; i += 256) {
    int idx = b*SCHUNK + i;
    if (idx < Nn) s += deg[idx];
  }
  sh[t] = s; __syncthreads();
  for (int o = 128; o; o >>= 1) { if (t < o) sh[t] += sh[t+o]; __syncthreads(); }
  if (!t) bsum[b] = sh[0];
}

__global__ void k_mid(const int* __restrict__ bsum, int* __restrict__ bpre, int* __restrict__ rowp)
{
  __shared__ int sh[NSB];
  int t = threadIdx.x;
  if (t < NSB) sh[t] = bsum[t];
  __syncthreads();
  if (!t) {
    int run = 0;
    for (int i = 0; i < NSB; ++i) { int v = sh[i]; sh[i] = run; run += v; }
    rowp[Nn] = run;
  }
  __syncthreads();
  if (t < NSB) bpre[t] = sh[t];
}

__global__ void k_scan(const int* __restrict__ deg, const int* __restrict__ bpre, int* __restrict__ rowp)
{
  __shared__ int sh[SCHUNK];
  int b = blockIdx.x, t = threadIdx.x;
  for (int i = t; i < SCHUNK; i += 256) {
    int idx = b*SCHUNK + i;
    sh[i] = (idx < Nn) ? deg[idx] : 0;
  }
  __syncthreads();
  if (!t) {
    int run = 0;
    for (int i = 0; i < SCHUNK; ++i) { int v = sh[i]; sh[i] = run; run += v; }
  }
  __syncthreads();
  int base = bpre[b];
  for (int i = t; i < SCHUNK; i += 256) {
    int idx = b*SCHUNK + i;
    if (idx < Nn) rowp[idx] = sh[i] + base;
  }
}

// fill + edge precompute: 12 per-(layer,head) projections (+kb), bf16-packed, + src
// into a 32-B record scattered to dst-sorted position (one per edge)
__global__ void k_fillpre(const int* __restrict__ src, const int* __restrict__ dst,
                          const float* __restrict__ eattr,
                          const float* __restrict__ Kmat, const float* __restrict__ kb,
                          const int* __restrict__ rowp, int* __restrict__ fill,
                          u32* __restrict__ rec)
{
  int e = blockIdx.x * 256 + threadIdx.x;
  if (e >= Ee) return;
  const float4* p = (const float4*)(eattr + (size_t)e * EDIM);
  float ea[16];
  #pragma unroll
  for (int qq = 0; qq < 4; ++qq) {
    float4 v = p[qq];
    ea[qq*4+0] = v.x; ea[qq*4+1] = v.y; ea[qq*4+2] = v.z; ea[qq*4+3] = v.w;
  }
  float ep[12];
  #pragma unroll
  for (int col = 0; col < 12; ++col) ep[col] = kb[col];
  #pragma unroll
  for (int k = 0; k < 16; ++k) {
    float v = ea[k];
    #pragma unroll
    for (int col = 0; col < 12; ++col) ep[col] += v * Kmat[k*12 + col];
  }
  int d = dst[e];
  int pos = rowp[d] + atomicAdd(&fill[d], 1);
  uint4 r0, r1;
  r0.x = bf16rne(ep[0])  | (bf16rne(ep[1])  << 16);
  r0.y = bf16rne(ep[2])  | (bf16rne(ep[3])  << 16);
  r0.z = bf16rne(ep[4])  | (bf16rne(ep[5])  << 16);
  r0.w = bf16rne(ep[6])  | (bf16rne(ep[7])  << 16);
  r1.x = bf16rne(ep[8])  | (bf16rne(ep[9])  << 16);
  r1.y = bf16rne(ep[10]) | (bf16rne(ep[11]) << 16);
  r1.z = (u32)src[e];
  r1.w = 0;
  uint4* rp = (uint4*)(rec + (size_t)pos * 8);
  rp[0] = r0; rp[1] = r1;
}

__device__ __forceinline__ int lbound(const int* __restrict__ a, int n, int key)
{
  int lo = 0, hi = n;
  while (lo < hi) {
    int mid = (lo + hi) >> 1;
    if (a[mid] < key) lo = mid + 1; else hi = mid;
  }
  return lo;
}

__global__ void k_gb(const int* __restrict__ batch, int* __restrict__ gb)
{
  int g = blockIdx.x * 256 + threadIdx.x;
  if (g <= Gg) gb[g] = lbound(batch, Nn, g);
}

// ---- BN(+ReLU) of prev layer + split-pack to bf16 hi/lo, in-place safe ----
__global__ void split_bn(const float* src, u32* dst,
                         const float* __restrict__ bnsum, const float* __restrict__ bnsq,
                         const float* __restrict__ gammaL, const float* __restrict__ betaL,
                         int apply_bn)
{
  int idx = blockIdx.x * 256 + threadIdx.x;
  if (idx >= Nn*HC/4) return;
  float4 v = ((const float4*)src)[idx];
  if (apply_bn) {
    int c = (idx * 4) & 127;
    float s0, t0, s1, t1, s2, t2, s3, t3;
    {
      float mu  = bnsum[c+0] * (1.f/Nn); float var = bnsq[c+0] * (1.f/Nn) - mu*mu;
      s0 = rsqrtf(var + BN_EPS) * gammaL[c+0]; t0 = betaL[c+0] - mu * s0;
    }
    {
      float mu  = bnsum[c+1] * (1.f/Nn); float var = bnsq[c+1] * (1.f/Nn) - mu*mu;
      s1 = rsqrtf(var + BN_EPS) * gammaL[c+1]; t1 = betaL[c+1] - mu * s1;
    }
    {
      float mu  = bnsum[c+2] * (1.f/Nn); float var = bnsq[c+2] * (1.f/Nn) - mu*mu;
      s2 = rsqrtf(var + BN_EPS) * gammaL[c+2]; t2 = betaL[c+2] - mu * s2;
    }
    {
      float mu  = bnsum[c+3] * (1.f/Nn); float var = bnsq[c+3] * (1.f/Nn) - mu*mu;
      s3 = rsqrtf(var + BN_EPS) * gammaL[c+3]; t3 = betaL[c+3] - mu * s3;
    }
    v.x = fmaxf(v.x*s0 + t0, 0.f);
    v.y = fmaxf(v.y*s1 + t1, 0.f);
    v.z = fmaxf(v.z*s2 + t2, 0.f);
    v.w = fmaxf(v.w*s3 + t3, 0.f);
  }
  uint4 o;
  o.x = packsplit(v.x); o.y = packsplit(v.y);
  o.z = packsplit(v.z); o.w = packsplit(v.w);
  ((uint4*)dst)[idx] = o;
}

// ---- MFMA GEMM, 64-row blocks; C as bf16; attn dots fused (f32 acc)
__global__ __launch_bounds__(256, 4) void gemm_mfma(const u32* __restrict__ Apk,
                                                    const u32* __restrict__ Wf,
                                                    u16* __restrict__ C2,
                                                    const float* __restrict__ aS,
                                                    const float* __restrict__ aD,
                                                    float* __restrict__ as_,
                                                    float* __restrict__ ad_)
{
  int t = threadIdx.x;
  int w = t >> 6, lane = t & 63;
  int col = lane & 15, q = lane >> 4;
  int rbase = blockIdx.x * 64 + w * 16;

  v4f acc[8];
  #pragma unroll
  for (int nt = 0; nt < 8; ++nt) acc[nt] = (v4f){0.f, 0.f, 0.f, 0.f};

  const uint4* Wf4 = (const uint4*)Wf;

  for (int ks = 0; ks < 4; ++ks) {
    PkAB Ah, Al;
    int ar = rbase + col;
    if (ar >= Nn) ar = Nn - 1;
    const uint4* pa = (const uint4*)(Apk + (size_t)ar*HC + ks*32 + q*8);
    uint4 r0 = pa[0], r1 = pa[1];
    Ah.u[0] = (r0.x & 0xFFFFu) | (r0.y << 16);
    Al.u[0] = (r0.x >> 16)     | (r0.y & 0xFFFF0000u);
    Ah.u[1] = (r0.z & 0xFFFFu) | (r0.w << 16);
    Al.u[1] = (r0.z >> 16)     | (r0.w & 0xFFFF0000u);
    Ah.u[2] = (r1.x & 0xFFFFu) | (r1.y << 16);
    Al.u[2] = (r1.x >> 16)     | (r1.y & 0xFFFF0000u);
    Ah.u[3] = (r1.z & 0xFFFFu) | (r1.w << 16);
    Al.u[3] = (r1.z >> 16)     | (r1.w & 0xFFFF0000u);
    #pragma unroll
    for (int nt = 0; nt < 8; ++nt) {
      uint4 b0 = Wf4[((nt*4 + ks)*2 + 0)*64 + lane];
      uint4 b1 = Wf4[((nt*4 + ks)*2 + 1)*64 + lane];
      PkAB Bh, Bl;
      Bh.u[0] = (b0.x & 0xFFFFu) | (b0.y << 16);
      Bl.u[0] = (b0.x >> 16)     | (b0.y & 0xFFFF0000u);
      Bh.u[1] = (b0.z & 0xFFFFu) | (b0.w << 16);
      Bl.u[1] = (b0.z >> 16)     | (b0.w & 0xFFFF0000u);
      Bh.u[2] = (b1.x & 0xFFFFu) | (b1.y << 16);
      Bl.u[2] = (b1.x >> 16)     | (b1.y & 0xFFFF0000u);
      Bh.u[3] = (b1.z & 0xFFFFu) | (b1.w << 16);
      Bl.u[3] = (b1.z >> 16)     | (b1.w & 0xFFFF0000u);
      acc[nt] = __builtin_amdgcn_mfma_f32_16x16x32_bf16(Ah.v, Bh.v, acc[nt], 0, 0, 0);
      acc[nt] = __builtin_amdgcn_mfma_f32_16x16x32_bf16(Ah.v, Bl.v, acc[nt], 0, 0, 0);
      acc[nt] = __builtin_amdgcn_mfma_f32_16x16x32_bf16(Al.v, Bh.v, acc[nt], 0, 0, 0);
    }
  }

  #pragma unroll
  for (int reg = 0; reg < 4; ++reg) {
    int row = rbase + q*4 + reg;
    if (row < Nn) {
      #pragma unroll
      for (int nt = 0; nt < 8; ++nt)
        C2[(size_t)row*HC + nt*16 + col] = (u16)bf16rne(acc[nt][reg]);
    }
  }

  #pragma unroll
  for (int h = 0; h < 4; ++h) {
    float a0 = aS[32*h + col], a1 = aS[32*h + 16 + col];
    float d0 = aD[32*h + col], d1 = aD[32*h + 16 + col];
    #pragma unroll
    for (int reg = 0; reg < 4; ++reg) {
      float s1 = acc[2*h][reg]*a0 + acc[2*h+1][reg]*a1;
      float s2 = acc[2*h][reg]*d0 + acc[2*h+1][reg]*d1;
      s1 += __shfl_xor(s1, 1); s1 += __shfl_xor(s1, 2);
      s1 += __shfl_xor(s1, 4); s1 += __shfl_xor(s1, 8);
      s2 += __shfl_xor(s2, 1); s2 += __shfl_xor(s2, 2);
      s2 += __shfl_xor(s2, 4); s2 += __shfl_xor(s2, 8);
      if (col == 0) {
        int row = rbase + q*4 + reg;
        if (row < Nn) {
          as_[row*NHD + h] = s1;
          ad_[row*NHD + h] = s2;
        }
      }
    }
  }
}

// CSR aggregation with fused alpha->leaky->exp; 32 thr/node, 8 nodes/block
__global__ __launch_bounds__(256) void aggregate(const int* __restrict__ rowp, const u32* __restrict__ rec,
                                                 const float* __restrict__ as_, const float* __restrict__ ad_,
                                                 int l, const u32* __restrict__ xl2,
                                                 const float* __restrict__ bias, float* __restrict__ outp)
{
  int n = blockIdx.x * 8 + (threadIdx.x >> 5);
  if (n >= Nn) return;
  int c4 = threadIdx.x & 31;        // channels c4*4 .. c4*4+3
  int h = c4 >> 3;
  int idx = l*4 + h;
  int p = idx >> 1, sel = idx & 1;
  float adh = ad_[n*NHD + h];
  int beg = rowp[n], end = rowp[n+1];
  float4 acc = make_float4(0.f,0.f,0.f,0.f);
  float wsum = 0.f;
  int i = beg;
  for (; i + 8 <= end; i += 8) {
    u32 eu[8]; int s[8]; float av[8]; uint2 v[8];
    #pragma unroll
    for (int j = 0; j < 8; ++j) eu[j] = rec[(size_t)(i+j)*8 + p];
    #pragma unroll
    for (int j = 0; j < 8; ++j) s[j] = (int)rec[(size_t)(i+j)*8 + 6];
    #pragma unroll
    for (int j = 0; j < 8; ++j) av[j] = as_[s[j]*NHD + h];
    #pragma unroll
    for (int j = 0; j < 8; ++j) v[j] = *(const uint2*)(xl2 + (size_t)s[j] * 64 + c4*2);
    #pragma unroll
    for (int j = 0; j < 8; ++j) {
      float ep = sel ? bfhi(eu[j]) : bflo(eu[j]);
      float a = ep + av[j] + adh;
      a = (a > 0.f) ? a : SLOPE * a;
      float wj = __expf(a);
      acc.x += wj*bflo(v[j].x); acc.y += wj*bfhi(v[j].x);
      acc.z += wj*bflo(v[j].y); acc.w += wj*bfhi(v[j].y);
      wsum += wj;
    }
  }
  for (; i < end; ++i) {
    u32 eu = rec[(size_t)i*8 + p];
    int s = (int)rec[(size_t)i*8 + 6];
    float ep = sel ? bfhi(eu) : bflo(eu);
    float a = ep + as_[s*NHD + h] + adh;
    a = (a > 0.f) ? a : SLOPE * a;
    float wj = __expf(a);
    uint2 v = *(const uint2*)(xl2 + (size_t)s * 64 + c4*2);
    acc.x += wj*bflo(v.x); acc.y += wj*bfhi(v.x);
    acc.z += wj*bflo(v.y); acc.w += wj*bfhi(v.y);
    wsum += wj;
  }
  float inv = 1.f / (wsum + 1e-16f);
  float4 b4 = *(const float4*)(bias + c4*4);
  float4 o;
  o.x = acc.x*inv + b4.x; o.y = acc.y*inv + b4.y;
  o.z = acc.z*inv + b4.z; o.w = acc.w*inv + b4.w;
  *(float4*)(outp + (size_t)n * HC + c4*4) = o;
}

__global__ void bn_reduce(const float* __restrict__ A, float* __restrict__ bnsum, float* __restrict__ bnsq)
{
  __shared__ float ss[256], sq[256];
  int t = threadIdx.x;
  int c = t & 127, hh = t >> 7;
  float s = 0.f, q = 0.f;
  for (int n = blockIdx.x * 2 + hh; n < Nn; n += gridDim.x * 2) {
    float v = A[(size_t)n * HC + c];
    s += v; q += v * v;
  }
  ss[t] = s; sq[t] = q;
  __syncthreads();
  if (t < 128) {
    atomicAdd(&bnsum[c], ss[t] + ss[t+128]);
    atomicAdd(&bnsq[c],  sq[t] + sq[t+128]);
  }
}

// mean-pool with final-layer BN+ReLU fused; per (graph x channel-quarter) block
__global__ __launch_bounds__(256) void pool2(const float* __restrict__ A, const int* __restrict__ gb,
                                             const float* __restrict__ bnsum, const float* __restrict__ bnsq,
                                             const float* __restrict__ gammaL, const float* __restrict__ betaL,
                                             float* __restrict__ pool)
{
  __shared__ float4 red[256];
  int g = blockIdx.x >> 2, qt = blockIdx.x & 3;
  int t = threadIdx.x;
  int cg = t & 7;
  int rs = t >> 3;
  int c4 = qt*8 + cg;
  int c = c4 * 4;
  int lo = gb[g], hi = gb[g+1];
  float s0, t0, s1, t1, s2, t2, s3, t3;
  {
    float mu = bnsum[c+0]*(1.f/Nn); float var = bnsq[c+0]*(1.f/Nn) - mu*mu;
    s0 = rsqrtf(var + BN_EPS) * gammaL[c+0]; t0 = betaL[c+0] - mu*s0;
  }
  {
    float mu = bnsum[c+1]*(1.f/Nn); float var = bnsq[c+1]*(1.f/Nn) - mu*mu;
    s1 = rsqrtf(var + BN_EPS) * gammaL[c+1]; t1 = betaL[c+1] - mu*s1;
  }
  {
    float mu = bnsum[c+2]*(1.f/Nn); float var = bnsq[c+2]*(1.f/Nn) - mu*mu;
    s2 = rsqrtf(var + BN_EPS) * gammaL[c+2]; t2 = betaL[c+2] - mu*s2;
  }
  {
    float mu = bnsum[c+3]*(1.f/Nn); float var = bnsq[c+3]*(1.f/Nn) - mu*mu;
    s3 = rsqrtf(var + BN_EPS) * gammaL[c+3]; t3 = betaL[c+3] - mu*s3;
  }
  float4 acc = make_float4(0.f,0.f,0.f,0.f);
  for (int n = lo + rs; n < hi; n += 32) {
    float4 v = *(const float4*)(A + (size_t)n*HC + c);
    acc.x += fmaxf(v.x*s0 + t0, 0.f);
    acc.y += fmaxf(v.y*s1 + t1, 0.f);
    acc.z += fmaxf(v.z*s2 + t2, 0.f);
    acc.w += fmaxf(v.w*s3 + t3, 0.f);
  }
  red[t] = acc;
  __syncthreads();
  for (int off = 128; off >= 8; off >>= 1) {
    if (t < off) {
      red[t].x += red[t+off].x; red[t].y += red[t+off].y;
      red[t].z += red[t+off].z; red[t].w += red[t+off].w;
    }
    __syncthreads();
  }
  if (t < 8) {
    float inv = 1.f / fmaxf((float)(hi - lo), 1.f);
    float4 r = red[t];
    r.x *= inv; r.y *= inv; r.z *= inv; r.w *= inv;
    *(float4*)(pool + (size_t)g*HC + qt*32 + t*4) = r;
  }
}

__global__ void final_fc(const float* __restrict__ pool,
                         const float* __restrict__ fcW, const float* __restrict__ fcb,
                         float* __restrict__ out)
{
  int t = blockIdx.x * 256 + threadIdx.x;
  if (t >= Gg * NOUT) return;
  int g = t >> 1, o = t & 1;
  float acc = 0.f;
  for (int k = 0; k < HC; ++k)
    acc += pool[(size_t)g * HC + k] * fcW[k * NOUT + o];
  out[t] = acc + fcb[o];
}

extern "C" void kernel_launch(void* const* d_in, const int* in_sizes, int n_in,
                              void* d_out, int out_size, void* d_ws, size_t ws_size,
                              hipStream_t stream)
{
  const float* x      = (const float*)d_in[0];
  const int*   eidx   = (const int*)d_in[1];
  const float* eattr  = (const float*)d_in[2];
  const int*   batch  = (const int*)d_in[3];
  const float* efcW   = (const float*)d_in[4];
  const float* efcb   = (const float*)d_in[5];
  const float* Wall   = (const float*)d_in[6];
  const float* attS   = (const float*)d_in[7];
  const float* attD   = (const float*)d_in[8];
  const float* attE   = (const float*)d_in[9];
  const float* linE   = (const float*)d_in[10];
  const float* biases = (const float*)d_in[11];
  const float* gamma  = (const float*)d_in[12];
  const float* beta   = (const float*)d_in[13];
  const float* fcW    = (const float*)d_in[14];
  const float* fcb    = (const float*)d_in[15];
  float* out = (float*)d_out;

  const int* src = eidx;
  const int* dst = eidx + Ee;

  float* ws    = (float*)d_ws;
  float* bufA  = ws;                            // N*128 (f32 / packed u32)
  float* bufB  = bufA + (size_t)Nn*HC;          // N*128 (u16 bf16 rows use half)
  float* as_   = bufB + (size_t)Nn*HC;          // N*4
  float* ad_   = as_ + (size_t)Nn*NHD;          // N*4
  float* Kmat  = ad_ + (size_t)Nn*NHD;          // 192
  float* kb    = Kmat + 192;                    // 16
  float* bnsum = kb + 16;                       // 128
  float* bnsq  = bnsum + 128;                   // 128
  float* pool  = bnsq + 128;                    // G*128 (offset stays 16B-aligned)
  u32*   rec   = (u32*)(pool + (size_t)Gg*HC);  // E*8 u32 (32-B records, 16B-aligned)
  u32*   Wf    = rec + (size_t)Ee*8;            // 3*128*128 u32 (16B-aligned)
  int*   gb    = (int*)(Wf + 3*HC*HC);          // Gg+1
  int*   rowp  = gb + (Gg + 3);                 // N+1
  int*   deg   = rowp + (Nn + 1);               // N
  int*   fill  = deg + Nn;                      // N (deg..fill one memset)
  int*   bsum  = fill + Nn;                     // NSB
  int*   bpre  = bsum + 128;                    // NSB

  w_split<<<(3*HC*HC + 255)/256, 256, 0, stream>>>(Wall, Wf);
  compute_K<<<1, 512, 0, stream>>>(efcW, efcb, linE, attE, Kmat, kb);
  k_gb<<<2, 256, 0, stream>>>(batch, gb);

  // CSR build + edge precompute (reused across all 3 layers)
  hipMemsetAsync(deg, 0, 2*Nn*sizeof(int), stream);
  k_hist<<<(Ee + 255)/256, 256, 0, stream>>>(dst, deg);
  k_bsum<<<NSB, 256, 0, stream>>>(deg, bsum);
  k_mid<<<1, 128, 0, stream>>>(bsum, bpre, rowp);
  k_scan<<<NSB, 256, 0, stream>>>(deg, bpre, rowp);
  k_fillpre<<<(Ee + 255)/256, 256, 0, stream>>>(src, dst, eattr, Kmat, kb, rowp, fill, rec);

  for (int l = 0; l < 3; ++l) {
    if (l == 0)
      split_bn<<<(Nn*HC/4 + 255)/256, 256, 0, stream>>>(x, (u32*)bufA, nullptr, nullptr, nullptr, nullptr, 0);
    else
      split_bn<<<(Nn*HC/4 + 255)/256, 256, 0, stream>>>(bufA, (u32*)bufA, bnsum, bnsq,
                                                        gamma + (l-1)*HC, beta + (l-1)*HC, 1);
    gemm_mfma<<<(Nn + 63)/64, 256, 0, stream>>>((const u32*)bufA, Wf + (size_t)l*HC*HC, (u16*)bufB,
                                                attS + l*HC, attD + l*HC, as_, ad_);
    aggregate<<<(Nn + 7)/8, 256, 0, stream>>>(rowp, rec, as_, ad_, l, (const u32*)bufB,
                                              biases + l*HC, bufA);
    hipMemsetAsync(bnsum, 0, 256*sizeof(float), stream);
    bn_reduce<<<1024, 256, 0, stream>>>(bufA, bnsum, bnsq);
  }

  pool2<<<Gg*4, 256, 0, stream>>>(bufA, gb, bnsum, bnsq, gamma + 2*HC, beta + 2*HC, pool);
  final_fc<<<2, 256, 0, stream>>>(pool, fcW, fcb, out);
}

// Round 13
// 716.215 us; speedup vs baseline: 1.3588x; 1.1136x over previous
//
#include <hip/hip_runtime.h>

#define Nn 100000
#define Ee 800000
#define HC 128
#define HID 32
#define NHD 4
#define EDIM 16
#define Gg 256
#define NOUT 2
#define SLOPE 0.2f
#define BN_EPS 1e-5f
#define SCHUNK 1024
#define NSB 98   // ceil(Nn/SCHUNK)
#define NSLOT 64

typedef unsigned int u32;
typedef unsigned short u16;
typedef short v8s __attribute__((ext_vector_type(8)));
typedef float v4f __attribute__((ext_vector_type(4)));

union PkAB { u32 u[4]; v8s v; };

__device__ __forceinline__ float bflo(u32 u){ return __uint_as_float(u << 16); }
__device__ __forceinline__ float bfhi(u32 u){ return __uint_as_float(u & 0xFFFF0000u); }

__device__ __forceinline__ u32 bf16rne(float x)
{
  u32 b = __float_as_uint(x);
  return (b + 0x7FFFu + ((b >> 16) & 1u)) >> 16;
}
__device__ __forceinline__ u32 packsplit(float x)
{
  u32 hb = bf16rne(x);
  float hf = __uint_as_float(hb << 16);
  u32 lb = bf16rne(x - hf);
  return hb | (lb << 16);
}
__device__ __forceinline__ void split2(float f, u32& hb, u32& lb)
{
  hb = bf16rne(f);
  lb = bf16rne(f - __uint_as_float(hb << 16));
}

// ---- tiny weight precompute: Kmat[16][12], kb[12] ----
__global__ void compute_K(const float* __restrict__ efcW, const float* __restrict__ efcb,
                          const float* __restrict__ linE, const float* __restrict__ attE,
                          float* __restrict__ Kmat, float* __restrict__ kb)
{
  __shared__ float Msh[384];
  int t = threadIdx.x;
  if (t < 384) {
    int l = t >> 7, j = (t >> 2) & 31, h = t & 3;
    float m = 0.f;
    for (int c = 0; c < 32; ++c)
      m += linE[(l*32 + j)*128 + h*32 + c] * attE[(l*4 + h)*32 + c];
    Msh[l*128 + j*4 + h] = m;
  }
  __syncthreads();
  if (t < 192) {
    int k = t / 12, col = t % 12, l = col >> 2, h = col & 3;
    float acc = 0.f;
    for (int j = 0; j < 32; ++j)
      acc += efcW[k*32 + j] * Msh[l*128 + j*4 + h];
    Kmat[k*12 + col] = acc;
  } else if (t < 204) {
    int col = t - 192, l = col >> 2, h = col & 3;
    float acc = 0.f;
    for (int j = 0; j < 32; ++j)
      acc += efcb[j] * Msh[l*128 + j*4 + h];
    kb[col] = acc;
  }
}

// ---- W -> split-bf16 MFMA B-fragment layout (once) ----
__global__ void w_split(const float* __restrict__ Wall, u32* __restrict__ Wf)
{
  int tid = blockIdx.x * 256 + threadIdx.x;
  if (tid >= 3*HC*HC) return;
  int l = tid / (HC*HC);
  int rem = tid - l*HC*HC;
  int k = rem >> 7, n = rem & 127;
  u32 p = packsplit(Wall[tid]);
  int nt = n >> 4, col = n & 15;
  int ks = k >> 5, kin = k & 31, q = kin >> 3, j = kin & 7;
  int half = j >> 2, j4 = j & 3;
  int idx = ((((l*8 + nt)*4 + ks)*2 + half)*64 + q*16 + col)*4 + j4;
  Wf[idx] = p;
}

// ---- CSR build ----
__global__ void k_hist(const int* __restrict__ dst, int* __restrict__ deg)
{
  int e = blockIdx.x * 256 + threadIdx.x;
  if (e < Ee) atomicAdd(&deg[dst[e]], 1);
}

__global__ void k_bsum(const int* __restrict__ deg, int* __restrict__ bsum)
{
  __shared__ int sh[256];
  int b = blockIdx.x, t = threadIdx.x;
  int s = 0;
  for (int i = t; i < SCHUNK; i += 256) {
    int idx = b*SCHUNK + i;
    if (idx < Nn) s += deg[idx];
  }
  sh[t] = s; __syncthreads();
  for (int o = 128; o; o >>= 1) { if (t < o) sh[t] += sh[t+o]; __syncthreads(); }
  if (!t) bsum[b] = sh[0];
}

__global__ void k_mid(const int* __restrict__ bsum, int* __restrict__ bpre, int* __restrict__ rowp)
{
  __shared__ int sh[NSB];
  int t = threadIdx.x;
  if (t < NSB) sh[t] = bsum[t];
  __syncthreads();
  if (!t) {
    int run = 0;
    for (int i = 0; i < NSB; ++i) { int v = sh[i]; sh[i] = run; run += v; }
    rowp[Nn] = run;
  }
  __syncthreads();
  if (t < NSB) bpre[t] = sh[t];
}

__global__ void k_scan(const int* __restrict__ deg, const int* __restrict__ bpre, int* __restrict__ rowp)
{
  __shared__ int sh[SCHUNK];
  int b = blockIdx.x, t = threadIdx.x;
  for (int i = t; i < SCHUNK; i += 256) {
    int idx = b*SCHUNK + i;
    sh[i] = (idx < Nn) ? deg[idx] : 0;
  }
  __syncthreads();
  if (!t) {
    int run = 0;
    for (int i = 0; i < SCHUNK; ++i) { int v = sh[i]; sh[i] = run; run += v; }
  }
  __syncthreads();
  int base = bpre[b];
  for (int i = t; i < SCHUNK; i += 256) {
    int idx = b*SCHUNK + i;
    if (idx < Nn) rowp[idx] = sh[i] + base;
  }
}

// fill + edge precompute into 32-B dst-sorted records
__global__ void k_fillpre(const int* __restrict__ src, const int* __restrict__ dst,
                          const float* __restrict__ eattr,
                          const float* __restrict__ Kmat, const float* __restrict__ kb,
                          const int* __restrict__ rowp, int* __restrict__ fill,
                          u32* __restrict__ rec)
{
  int e = blockIdx.x * 256 + threadIdx.x;
  if (e >= Ee) return;
  const float4* p = (const float4*)(eattr + (size_t)e * EDIM);
  float ea[16];
  #pragma unroll
  for (int qq = 0; qq < 4; ++qq) {
    float4 v = p[qq];
    ea[qq*4+0] = v.x; ea[qq*4+1] = v.y; ea[qq*4+2] = v.z; ea[qq*4+3] = v.w;
  }
  float ep[12];
  #pragma unroll
  for (int col = 0; col < 12; ++col) ep[col] = kb[col];
  #pragma unroll
  for (int k = 0; k < 16; ++k) {
    float v = ea[k];
    #pragma unroll
    for (int col = 0; col < 12; ++col) ep[col] += v * Kmat[k*12 + col];
  }
  int d = dst[e];
  int pos = rowp[d] + atomicAdd(&fill[d], 1);
  uint4 r0, r1;
  r0.x = bf16rne(ep[0])  | (bf16rne(ep[1])  << 16);
  r0.y = bf16rne(ep[2])  | (bf16rne(ep[3])  << 16);
  r0.z = bf16rne(ep[4])  | (bf16rne(ep[5])  << 16);
  r0.w = bf16rne(ep[6])  | (bf16rne(ep[7])  << 16);
  r1.x = bf16rne(ep[8])  | (bf16rne(ep[9])  << 16);
  r1.y = bf16rne(ep[10]) | (bf16rne(ep[11]) << 16);
  r1.z = (u32)src[e];
  r1.w = 0;
  uint4* rp = (uint4*)(rec + (size_t)pos * 8);
  rp[0] = r0; rp[1] = r1;
}

__device__ __forceinline__ int lbound(const int* __restrict__ a, int n, int key)
{
  int lo = 0, hi = n;
  while (lo < hi) {
    int mid = (lo + hi) >> 1;
    if (a[mid] < key) lo = mid + 1; else hi = mid;
  }
  return lo;
}

__global__ void k_gb(const int* __restrict__ batch, int* __restrict__ gb)
{
  int g = blockIdx.x * 256 + threadIdx.x;
  if (g <= Gg) gb[g] = lbound(batch, Nn, g);
}

// pack x (no BN) once
__global__ void split_x(const float* __restrict__ src, u32* __restrict__ dst)
{
  int idx = blockIdx.x * 256 + threadIdx.x;
  if (idx >= Nn*HC/4) return;
  float4 v = ((const float4*)src)[idx];
  uint4 o;
  o.x = packsplit(v.x); o.y = packsplit(v.y);
  o.z = packsplit(v.z); o.w = packsplit(v.w);
  ((uint4*)dst)[idx] = o;
}

// ---- MFMA GEMM, 64-row blocks; BN+ReLU of prev layer applied at A-load (scb/shb);
// C as bf16; attn dots fused (f32 acc)
__global__ __launch_bounds__(256, 4) void gemm_mfma(const u32* __restrict__ Apk,
                                                    const u32* __restrict__ Wf,
                                                    u16* __restrict__ C2,
                                                    const float* __restrict__ aS,
                                                    const float* __restrict__ aD,
                                                    float* __restrict__ as_,
                                                    float* __restrict__ ad_,
                                                    const float* __restrict__ scb,
                                                    const float* __restrict__ shb,
                                                    int apply_bn)
{
  int t = threadIdx.x;
  int w = t >> 6, lane = t & 63;
  int col = lane & 15, q = lane >> 4;
  int rbase = blockIdx.x * 64 + w * 16;

  v4f acc[8];
  #pragma unroll
  for (int nt = 0; nt < 8; ++nt) acc[nt] = (v4f){0.f, 0.f, 0.f, 0.f};

  const uint4* Wf4 = (const uint4*)Wf;

  for (int ks = 0; ks < 4; ++ks) {
    PkAB Ah, Al;
    int ar = rbase + col;
    if (ar >= Nn) ar = Nn - 1;
    int cb = ks*32 + q*8;
    const uint4* pa = (const uint4*)(Apk + (size_t)ar*HC + cb);
    uint4 r0 = pa[0], r1 = pa[1];
    if (!apply_bn) {
      // exact bit shuffle of pre-packed hi/lo
      Ah.u[0] = (r0.x & 0xFFFFu) | (r0.y << 16);
      Al.u[0] = (r0.x >> 16)     | (r0.y & 0xFFFF0000u);
      Ah.u[1] = (r0.z & 0xFFFFu) | (r0.w << 16);
      Al.u[1] = (r0.z >> 16)     | (r0.w & 0xFFFF0000u);
      Ah.u[2] = (r1.x & 0xFFFFu) | (r1.y << 16);
      Al.u[2] = (r1.x >> 16)     | (r1.y & 0xFFFF0000u);
      Ah.u[3] = (r1.z & 0xFFFFu) | (r1.w << 16);
      Al.u[3] = (r1.z >> 16)     | (r1.w & 0xFFFF0000u);
    } else {
      float4 sc0 = *(const float4*)(scb + cb), sc1 = *(const float4*)(scb + cb + 4);
      float4 sh0 = *(const float4*)(shb + cb), sh1 = *(const float4*)(shb + cb + 4);
      float f0 = fmaxf((bflo(r0.x)+bfhi(r0.x))*sc0.x + sh0.x, 0.f);
      float f1 = fmaxf((bflo(r0.y)+bfhi(r0.y))*sc0.y + sh0.y, 0.f);
      float f2 = fmaxf((bflo(r0.z)+bfhi(r0.z))*sc0.z + sh0.z, 0.f);
      float f3 = fmaxf((bflo(r0.w)+bfhi(r0.w))*sc0.w + sh0.w, 0.f);
      float f4 = fmaxf((bflo(r1.x)+bfhi(r1.x))*sc1.x + sh1.x, 0.f);
      float f5 = fmaxf((bflo(r1.y)+bfhi(r1.y))*sc1.y + sh1.y, 0.f);
      float f6 = fmaxf((bflo(r1.z)+bfhi(r1.z))*sc1.z + sh1.z, 0.f);
      float f7 = fmaxf((bflo(r1.w)+bfhi(r1.w))*sc1.w + sh1.w, 0.f);
      u32 hb0,lb0,hb1,lb1,hb2,lb2,hb3,lb3,hb4,lb4,hb5,lb5,hb6,lb6,hb7,lb7;
      split2(f0,hb0,lb0); split2(f1,hb1,lb1); split2(f2,hb2,lb2); split2(f3,hb3,lb3);
      split2(f4,hb4,lb4); split2(f5,hb5,lb5); split2(f6,hb6,lb6); split2(f7,hb7,lb7);
      Ah.u[0] = hb0 | (hb1 << 16);  Al.u[0] = lb0 | (lb1 << 16);
      Ah.u[1] = hb2 | (hb3 << 16);  Al.u[1] = lb2 | (lb3 << 16);
      Ah.u[2] = hb4 | (hb5 << 16);  Al.u[2] = lb4 | (lb5 << 16);
      Ah.u[3] = hb6 | (hb7 << 16);  Al.u[3] = lb6 | (lb7 << 16);
    }
    #pragma unroll
    for (int nt = 0; nt < 8; ++nt) {
      uint4 b0 = Wf4[((nt*4 + ks)*2 + 0)*64 + lane];
      uint4 b1 = Wf4[((nt*4 + ks)*2 + 1)*64 + lane];
      PkAB Bh, Bl;
      Bh.u[0] = (b0.x & 0xFFFFu) | (b0.y << 16);
      Bl.u[0] = (b0.x >> 16)     | (b0.y & 0xFFFF0000u);
      Bh.u[1] = (b0.z & 0xFFFFu) | (b0.w << 16);
      Bl.u[1] = (b0.z >> 16)     | (b0.w & 0xFFFF0000u);
      Bh.u[2] = (b1.x & 0xFFFFu) | (b1.y << 16);
      Bl.u[2] = (b1.x >> 16)     | (b1.y & 0xFFFF0000u);
      Bh.u[3] = (b1.z & 0xFFFFu) | (b1.w << 16);
      Bl.u[3] = (b1.z >> 16)     | (b1.w & 0xFFFF0000u);
      acc[nt] = __builtin_amdgcn_mfma_f32_16x16x32_bf16(Ah.v, Bh.v, acc[nt], 0, 0, 0);
      acc[nt] = __builtin_amdgcn_mfma_f32_16x16x32_bf16(Ah.v, Bl.v, acc[nt], 0, 0, 0);
      acc[nt] = __builtin_amdgcn_mfma_f32_16x16x32_bf16(Al.v, Bh.v, acc[nt], 0, 0, 0);
    }
  }

  #pragma unroll
  for (int reg = 0; reg < 4; ++reg) {
    int row = rbase + q*4 + reg;
    if (row < Nn) {
      #pragma unroll
      for (int nt = 0; nt < 8; ++nt)
        C2[(size_t)row*HC + nt*16 + col] = (u16)bf16rne(acc[nt][reg]);
    }
  }

  #pragma unroll
  for (int h = 0; h < 4; ++h) {
    float a0 = aS[32*h + col], a1 = aS[32*h + 16 + col];
    float d0 = aD[32*h + col], d1 = aD[32*h + 16 + col];
    #pragma unroll
    for (int reg = 0; reg < 4; ++reg) {
      float s1 = acc[2*h][reg]*a0 + acc[2*h+1][reg]*a1;
      float s2 = acc[2*h][reg]*d0 + acc[2*h+1][reg]*d1;
      s1 += __shfl_xor(s1, 1); s1 += __shfl_xor(s1, 2);
      s1 += __shfl_xor(s1, 4); s1 += __shfl_xor(s1, 8);
      s2 += __shfl_xor(s2, 1); s2 += __shfl_xor(s2, 2);
      s2 += __shfl_xor(s2, 4); s2 += __shfl_xor(s2, 8);
      if (col == 0) {
        int row = rbase + q*4 + reg;
        if (row < Nn) {
          as_[row*NHD + h] = s1;
          ad_[row*NHD + h] = s2;
        }
      }
    }
  }
}

// CSR aggregation with fused alpha->leaky->exp; packed output + BN partial sums
__global__ __launch_bounds__(256) void aggregate(const int* __restrict__ rowp, const u32* __restrict__ rec,
                                                 const float* __restrict__ as_, const float* __restrict__ ad_,
                                                 int l, const u32* __restrict__ xl2,
                                                 const float* __restrict__ bias, u32* __restrict__ outp,
                                                 float* __restrict__ psum, float* __restrict__ psq)
{
  __shared__ float4 rsum[256];
  __shared__ float4 rsq[256];
  int t = threadIdx.x;
  int n = blockIdx.x * 8 + (t >> 5);
  int c4 = t & 31;
  int h = c4 >> 3;
  float4 o = make_float4(0.f,0.f,0.f,0.f);
  bool valid = (n < Nn);
  if (valid) {
    int idx = l*4 + h;
    int p = idx >> 1, sel = idx & 1;
    float adh = ad_[n*NHD + h];
    int beg = rowp[n], end = rowp[n+1];
    float4 acc = make_float4(0.f,0.f,0.f,0.f);
    float wsum = 0.f;
    int i = beg;
    for (; i + 8 <= end; i += 8) {
      u32 eu[8]; int s[8]; float av[8]; uint2 v[8];
      #pragma unroll
      for (int j = 0; j < 8; ++j) eu[j] = rec[(size_t)(i+j)*8 + p];
      #pragma unroll
      for (int j = 0; j < 8; ++j) s[j] = (int)rec[(size_t)(i+j)*8 + 6];
      #pragma unroll
      for (int j = 0; j < 8; ++j) av[j] = as_[s[j]*NHD + h];
      #pragma unroll
      for (int j = 0; j < 8; ++j) v[j] = *(const uint2*)(xl2 + (size_t)s[j] * 64 + c4*2);
      #pragma unroll
      for (int j = 0; j < 8; ++j) {
        float ep = sel ? bfhi(eu[j]) : bflo(eu[j]);
        float a = ep + av[j] + adh;
        a = (a > 0.f) ? a : SLOPE * a;
        float wj = __expf(a);
        acc.x += wj*bflo(v[j].x); acc.y += wj*bfhi(v[j].x);
        acc.z += wj*bflo(v[j].y); acc.w += wj*bfhi(v[j].y);
        wsum += wj;
      }
    }
    for (; i < end; ++i) {
      u32 eu = rec[(size_t)i*8 + p];
      int s = (int)rec[(size_t)i*8 + 6];
      float ep = sel ? bfhi(eu) : bflo(eu);
      float a = ep + as_[s*NHD + h] + adh;
      a = (a > 0.f) ? a : SLOPE * a;
      float wj = __expf(a);
      uint2 v = *(const uint2*)(xl2 + (size_t)s * 64 + c4*2);
      acc.x += wj*bflo(v.x); acc.y += wj*bfhi(v.x);
      acc.z += wj*bflo(v.y); acc.w += wj*bfhi(v.y);
      wsum += wj;
    }
    float inv = 1.f / (wsum + 1e-16f);
    float4 b4 = *(const float4*)(bias + c4*4);
    o.x = acc.x*inv + b4.x; o.y = acc.y*inv + b4.y;
    o.z = acc.z*inv + b4.z; o.w = acc.w*inv + b4.w;
    uint4 w;
    w.x = packsplit(o.x); w.y = packsplit(o.y);
    w.z = packsplit(o.z); w.w = packsplit(o.w);
    *(uint4*)(outp + (size_t)n * HC + c4*4) = w;
  }
  // BN partial sums (invalid nodes contribute 0)
  rsum[t] = o;
  rsq[t] = make_float4(o.x*o.x, o.y*o.y, o.z*o.z, o.w*o.w);
  __syncthreads();
  for (int off = 128; off >= 32; off >>= 1) {
    if (t < off) {
      rsum[t].x += rsum[t+off].x; rsum[t].y += rsum[t+off].y;
      rsum[t].z += rsum[t+off].z; rsum[t].w += rsum[t+off].w;
      rsq[t].x  += rsq[t+off].x;  rsq[t].y  += rsq[t+off].y;
      rsq[t].z  += rsq[t+off].z;  rsq[t].w  += rsq[t+off].w;
    }
    __syncthreads();
  }
  if (t < 32) {
    int slot = blockIdx.x & (NSLOT-1);
    float4 s = rsum[t], q = rsq[t];
    atomicAdd(&psum[slot*HC + t*4+0], s.x);
    atomicAdd(&psum[slot*HC + t*4+1], s.y);
    atomicAdd(&psum[slot*HC + t*4+2], s.z);
    atomicAdd(&psum[slot*HC + t*4+3], s.w);
    atomicAdd(&psq[slot*HC + t*4+0], q.x);
    atomicAdd(&psq[slot*HC + t*4+1], q.y);
    atomicAdd(&psq[slot*HC + t*4+2], q.z);
    atomicAdd(&psq[slot*HC + t*4+3], q.w);
  }
}

// fold BN partial slots -> per-channel scale/shift; zero slots for next layer
__global__ void bn_final(float* __restrict__ psum, float* __restrict__ psq,
                         const float* __restrict__ gammaL, const float* __restrict__ betaL,
                         float* __restrict__ scb, float* __restrict__ shb)
{
  int c = threadIdx.x;   // 128
  float s = 0.f, q = 0.f;
  for (int k = 0; k < NSLOT; ++k) {
    s += psum[k*HC + c]; q += psq[k*HC + c];
    psum[k*HC + c] = 0.f; psq[k*HC + c] = 0.f;
  }
  float mu  = s * (1.f / Nn);
  float var = q * (1.f / Nn) - mu * mu;
  float sc = rsqrtf(var + BN_EPS) * gammaL[c];
  scb[c] = sc;
  shb[c] = betaL[c] - mu * sc;
}

// mean-pool over packed input with final-layer BN+ReLU (scb/shb)
__global__ __launch_bounds__(256) void pool2(const u32* __restrict__ Ap, const int* __restrict__ gb,
                                             const float* __restrict__ scb, const float* __restrict__ shb,
                                             float* __restrict__ pool)
{
  __shared__ float4 red[256];
  int g = blockIdx.x >> 2, qt = blockIdx.x & 3;
  int t = threadIdx.x;
  int cg = t & 7;
  int rs = t >> 3;
  int c4 = qt*8 + cg;
  int c = c4 * 4;
  int lo = gb[g], hi = gb[g+1];
  float4 s4 = *(const float4*)(scb + c);
  float4 t4 = *(const float4*)(shb + c);
  float4 acc = make_float4(0.f,0.f,0.f,0.f);
  for (int n = lo + rs; n < hi; n += 32) {
    uint4 v = *(const uint4*)(Ap + (size_t)n*HC + c);
    acc.x += fmaxf((bflo(v.x)+bfhi(v.x))*s4.x + t4.x, 0.f);
    acc.y += fmaxf((bflo(v.y)+bfhi(v.y))*s4.y + t4.y, 0.f);
    acc.z += fmaxf((bflo(v.z)+bfhi(v.z))*s4.z + t4.z, 0.f);
    acc.w += fmaxf((bflo(v.w)+bfhi(v.w))*s4.w + t4.w, 0.f);
  }
  red[t] = acc;
  __syncthreads();
  for (int off = 128; off >= 8; off >>= 1) {
    if (t < off) {
      red[t].x += red[t+off].x; red[t].y += red[t+off].y;
      red[t].z += red[t+off].z; red[t].w += red[t+off].w;
    }
    __syncthreads();
  }
  if (t < 8) {
    float inv = 1.f / fmaxf((float)(hi - lo), 1.f);
    float4 r = red[t];
    r.x *= inv; r.y *= inv; r.z *= inv; r.w *= inv;
    *(float4*)(pool + (size_t)g*HC + qt*32 + t*4) = r;
  }
}

__global__ void final_fc(const float* __restrict__ pool,
                         const float* __restrict__ fcW, const float* __restrict__ fcb,
                         float* __restrict__ out)
{
  int t = blockIdx.x * 256 + threadIdx.x;
  if (t >= Gg * NOUT) return;
  int g = t >> 1, o = t & 1;
  float acc = 0.f;
  for (int k = 0; k < HC; ++k)
    acc += pool[(size_t)g * HC + k] * fcW[k * NOUT + o];
  out[t] = acc + fcb[o];
}

extern "C" void kernel_launch(void* const* d_in, const int* in_sizes, int n_in,
                              void* d_out, int out_size, void* d_ws, size_t ws_size,
                              hipStream_t stream)
{
  const float* x      = (const float*)d_in[0];
  const int*   eidx   = (const int*)d_in[1];
  const float* eattr  = (const float*)d_in[2];
  const int*   batch  = (const int*)d_in[3];
  const float* efcW   = (const float*)d_in[4];
  const float* efcb   = (const float*)d_in[5];
  const float* Wall   = (const float*)d_in[6];
  const float* attS   = (const float*)d_in[7];
  const float* attD   = (const float*)d_in[8];
  const float* attE   = (const float*)d_in[9];
  const float* linE   = (const float*)d_in[10];
  const float* biases = (const float*)d_in[11];
  const float* gamma  = (const float*)d_in[12];
  const float* beta   = (const float*)d_in[13];
  const float* fcW    = (const float*)d_in[14];
  const float* fcb    = (const float*)d_in[15];
  float* out = (float*)d_out;

  const int* src = eidx;
  const int* dst = eidx + Ee;

  float* ws    = (float*)d_ws;
  float* bufA  = ws;                            // N*128 packed u32
  float* bufB  = bufA + (size_t)Nn*HC;          // N*128 (u16 bf16 rows use half)
  float* as_   = bufB + (size_t)Nn*HC;          // N*4
  float* ad_   = as_ + (size_t)Nn*NHD;          // N*4
  float* Kmat  = ad_ + (size_t)Nn*NHD;          // 192
  float* kb    = Kmat + 192;                    // 16
  float* scb   = kb + 16;                       // 128
  float* shb   = scb + 128;                     // 128
  float* pool  = shb + 128;                     // G*128 (16B-aligned)
  u32*   rec   = (u32*)(pool + (size_t)Gg*HC);  // E*8 u32 (32-B records)
  u32*   Wf    = rec + (size_t)Ee*8;            // 3*128*128 u32
  float* psum  = (float*)(Wf + 3*HC*HC);        // NSLOT*128
  float* psq   = psum + NSLOT*HC;               // NSLOT*128
  int*   gb    = (int*)(psq + NSLOT*HC);        // Gg+1
  int*   rowp  = gb + (Gg + 3);                 // N+1
  int*   deg   = rowp + (Nn + 1);               // N
  int*   fill  = deg + Nn;                      // N (deg..fill one memset)
  int*   bsum  = fill + Nn;                     // NSB
  int*   bpre  = bsum + 128;                    // NSB

  w_split<<<(3*HC*HC + 255)/256, 256, 0, stream>>>(Wall, Wf);
  compute_K<<<1, 512, 0, stream>>>(efcW, efcb, linE, attE, Kmat, kb);
  k_gb<<<2, 256, 0, stream>>>(batch, gb);

  // CSR build + edge precompute (reused across all 3 layers)
  hipMemsetAsync(deg, 0, 2*Nn*sizeof(int), stream);
  hipMemsetAsync(psum, 0, 2*NSLOT*HC*sizeof(float), stream);
  k_hist<<<(Ee + 255)/256, 256, 0, stream>>>(dst, deg);
  k_bsum<<<NSB, 256, 0, stream>>>(deg, bsum);
  k_mid<<<1, 128, 0, stream>>>(bsum, bpre, rowp);
  k_scan<<<NSB, 256, 0, stream>>>(deg, bpre, rowp);
  k_fillpre<<<(Ee + 255)/256, 256, 0, stream>>>(src, dst, eattr, Kmat, kb, rowp, fill, rec);

  split_x<<<(Nn*HC/4 + 255)/256, 256, 0, stream>>>(x, (u32*)bufA);

  for (int l = 0; l < 3; ++l) {
    gemm_mfma<<<(Nn + 63)/64, 256, 0, stream>>>((const u32*)bufA, Wf + (size_t)l*HC*HC, (u16*)bufB,
                                                attS + l*HC, attD + l*HC, as_, ad_,
                                                scb, shb, (l > 0) ? 1 : 0);
    aggregate<<<(Nn + 7)/8, 256, 0, stream>>>(rowp, rec, as_, ad_, l, (const u32*)bufB,
                                              biases + l*HC, (u32*)bufA, psum, psq);
    bn_final<<<1, 128, 0, stream>>>(psum, psq, gamma + l*HC, beta + l*HC, scb, shb);
  }

  pool2<<<Gg*4, 256, 0, stream>>>((const u32*)bufA, gb, scb, shb, pool);
  final_fc<<<2, 256, 0, stream>>>(pool, fcW, fcb, out);
}

// Round 14
// 647.809 us; speedup vs baseline: 1.5022x; 1.1056x over previous
//
#include <hip/hip_runtime.h>

#define Nn 100000
#define Ee 800000
#define HC 128
#define HID 32
#define NHD 4
#define EDIM 16
#define Gg 256
#define NOUT 2
#define SLOPE 0.2f
#define BN_EPS 1e-5f
#define SCHUNK 1024
#define NSB 98    // ceil(Nn/SCHUNK)
#define NBAG 6250 // ceil(Nn/16) aggregate blocks / BN slots

typedef unsigned int u32;
typedef unsigned short u16;
typedef short v8s __attribute__((ext_vector_type(8)));
typedef float v4f __attribute__((ext_vector_type(4)));

union PkAB { u32 u[4]; v8s v; };

__device__ __forceinline__ float bflo(u32 u){ return __uint_as_float(u << 16); }
__device__ __forceinline__ float bfhi(u32 u){ return __uint_as_float(u & 0xFFFF0000u); }

__device__ __forceinline__ u32 bf16rne(float x)
{
  u32 b = __float_as_uint(x);
  return (b + 0x7FFFu + ((b >> 16) & 1u)) >> 16;
}
__device__ __forceinline__ u32 packsplit(float x)
{
  u32 hb = bf16rne(x);
  float hf = __uint_as_float(hb << 16);
  u32 lb = bf16rne(x - hf);
  return hb | (lb << 16);
}
__device__ __forceinline__ void split2(float f, u32& hb, u32& lb)
{
  hb = bf16rne(f);
  lb = bf16rne(f - __uint_as_float(hb << 16));
}

// ---- tiny weight precompute: Kmat[16][12], kb[12] ----
__global__ void compute_K(const float* __restrict__ efcW, const float* __restrict__ efcb,
                          const float* __restrict__ linE, const float* __restrict__ attE,
                          float* __restrict__ Kmat, float* __restrict__ kb)
{
  __shared__ float Msh[384];
  int t = threadIdx.x;
  if (t < 384) {
    int l = t >> 7, j = (t >> 2) & 31, h = t & 3;
    float m = 0.f;
    for (int c = 0; c < 32; ++c)
      m += linE[(l*32 + j)*128 + h*32 + c] * attE[(l*4 + h)*32 + c];
    Msh[l*128 + j*4 + h] = m;
  }
  __syncthreads();
  if (t < 192) {
    int k = t / 12, col = t % 12, l = col >> 2, h = col & 3;
    float acc = 0.f;
    for (int j = 0; j < 32; ++j)
      acc += efcW[k*32 + j] * Msh[l*128 + j*4 + h];
    Kmat[k*12 + col] = acc;
  } else if (t < 204) {
    int col = t - 192, l = col >> 2, h = col & 3;
    float acc = 0.f;
    for (int j = 0; j < 32; ++j)
      acc += efcb[j] * Msh[l*128 + j*4 + h];
    kb[col] = acc;
  }
}

// ---- W -> split-bf16 MFMA B-fragment layout (once) ----
__global__ void w_split(const float* __restrict__ Wall, u32* __restrict__ Wf)
{
  int tid = blockIdx.x * 256 + threadIdx.x;
  if (tid >= 3*HC*HC) return;
  int l = tid / (HC*HC);
  int rem = tid - l*HC*HC;
  int k = rem >> 7, n = rem & 127;
  u32 p = packsplit(Wall[tid]);
  int nt = n >> 4, col = n & 15;
  int ks = k >> 5, kin = k & 31, q = kin >> 3, j = kin & 7;
  int half = j >> 2, j4 = j & 3;
  int idx = ((((l*8 + nt)*4 + ks)*2 + half)*64 + q*16 + col)*4 + j4;
  Wf[idx] = p;
}

// ---- CSR build ----
__global__ void k_hist(const int* __restrict__ dst, int* __restrict__ deg)
{
  int e = blockIdx.x * 256 + threadIdx.x;
  if (e < Ee) atomicAdd(&deg[dst[e]], 1);
}

__global__ void k_bsum(const int* __restrict__ deg, int* __restrict__ bsum)
{
  __shared__ int sh[256];
  int b = blockIdx.x, t = threadIdx.x;
  int s = 0;
  for (int i = t; i < SCHUNK; i += 256) {
    int idx = b*SCHUNK + i;
    if (idx < Nn) s += deg[idx];
  }
  sh[t] = s; __syncthreads();
  for (int o = 128; o; o >>= 1) { if (t < o) sh[t] += sh[t+o]; __syncthreads(); }
  if (!t) bsum[b] = sh[0];
}

__global__ void k_mid(const int* __restrict__ bsum, int* __restrict__ bpre, int* __restrict__ rowp)
{
  __shared__ int sh[NSB];
  int t = threadIdx.x;
  if (t < NSB) sh[t] = bsum[t];
  __syncthreads();
  if (!t) {
    int run = 0;
    for (int i = 0; i < NSB; ++i) { int v = sh[i]; sh[i] = run; run += v; }
    rowp[Nn] = run;
  }
  __syncthreads();
  if (t < NSB) bpre[t] = sh[t];
}

__global__ void k_scan(const int* __restrict__ deg, const int* __restrict__ bpre, int* __restrict__ rowp)
{
  __shared__ int sh[SCHUNK];
  int b = blockIdx.x, t = threadIdx.x;
  for (int i = t; i < SCHUNK; i += 256) {
    int idx = b*SCHUNK + i;
    sh[i] = (idx < Nn) ? deg[idx] : 0;
  }
  __syncthreads();
  if (!t) {
    int run = 0;
    for (int i = 0; i < SCHUNK; ++i) { int v = sh[i]; sh[i] = run; run += v; }
  }
  __syncthreads();
  int base = bpre[b];
  for (int i = t; i < SCHUNK; i += 256) {
    int idx = b*SCHUNK + i;
    if (idx < Nn) rowp[idx] = sh[i] + base;
  }
}

// fill + edge precompute into 32-B dst-sorted records
__global__ void k_fillpre(const int* __restrict__ src, const int* __restrict__ dst,
                          const float* __restrict__ eattr,
                          const float* __restrict__ Kmat, const float* __restrict__ kb,
                          const int* __restrict__ rowp, int* __restrict__ fill,
                          u32* __restrict__ rec)
{
  int e = blockIdx.x * 256 + threadIdx.x;
  if (e >= Ee) return;
  const float4* p = (const float4*)(eattr + (size_t)e * EDIM);
  float ea[16];
  #pragma unroll
  for (int qq = 0; qq < 4; ++qq) {
    float4 v = p[qq];
    ea[qq*4+0] = v.x; ea[qq*4+1] = v.y; ea[qq*4+2] = v.z; ea[qq*4+3] = v.w;
  }
  float ep[12];
  #pragma unroll
  for (int col = 0; col < 12; ++col) ep[col] = kb[col];
  #pragma unroll
  for (int k = 0; k < 16; ++k) {
    float v = ea[k];
    #pragma unroll
    for (int col = 0; col < 12; ++col) ep[col] += v * Kmat[k*12 + col];
  }
  int d = dst[e];
  int pos = rowp[d] + atomicAdd(&fill[d], 1);
  uint4 r0, r1;
  r0.x = bf16rne(ep[0])  | (bf16rne(ep[1])  << 16);
  r0.y = bf16rne(ep[2])  | (bf16rne(ep[3])  << 16);
  r0.z = bf16rne(ep[4])  | (bf16rne(ep[5])  << 16);
  r0.w = bf16rne(ep[6])  | (bf16rne(ep[7])  << 16);
  r1.x = bf16rne(ep[8])  | (bf16rne(ep[9])  << 16);
  r1.y = bf16rne(ep[10]) | (bf16rne(ep[11]) << 16);
  r1.z = (u32)src[e];
  r1.w = 0;
  uint4* rp = (uint4*)(rec + (size_t)pos * 8);
  rp[0] = r0; rp[1] = r1;
}

__device__ __forceinline__ int lbound(const int* __restrict__ a, int n, int key)
{
  int lo = 0, hi = n;
  while (lo < hi) {
    int mid = (lo + hi) >> 1;
    if (a[mid] < key) lo = mid + 1; else hi = mid;
  }
  return lo;
}

__global__ void k_gb(const int* __restrict__ batch, int* __restrict__ gb)
{
  int g = blockIdx.x * 256 + threadIdx.x;
  if (g <= Gg) gb[g] = lbound(batch, Nn, g);
}

// pack x (no BN) once
__global__ void split_x(const float* __restrict__ src, u32* __restrict__ dst)
{
  int idx = blockIdx.x * 256 + threadIdx.x;
  if (idx >= Nn*HC/4) return;
  float4 v = ((const float4*)src)[idx];
  uint4 o;
  o.x = packsplit(v.x); o.y = packsplit(v.y);
  o.z = packsplit(v.z); o.w = packsplit(v.w);
  ((uint4*)dst)[idx] = o;
}

// ---- MFMA GEMM, 64-row blocks; BN+ReLU of prev layer applied at A-load (scb/shb);
// C as bf16; attn dots fused (f32 acc). All 8 A-uint4s preloaded before k-loop.
__global__ __launch_bounds__(256, 4) void gemm_mfma(const u32* __restrict__ Apk,
                                                    const u32* __restrict__ Wf,
                                                    u16* __restrict__ C2,
                                                    const float* __restrict__ aS,
                                                    const float* __restrict__ aD,
                                                    float* __restrict__ as_,
                                                    float* __restrict__ ad_,
                                                    const float* __restrict__ scb,
                                                    const float* __restrict__ shb,
                                                    int apply_bn)
{
  int t = threadIdx.x;
  int w = t >> 6, lane = t & 63;
  int col = lane & 15, q = lane >> 4;
  int rbase = blockIdx.x * 64 + w * 16;

  v4f acc[8];
  #pragma unroll
  for (int nt = 0; nt < 8; ++nt) acc[nt] = (v4f){0.f, 0.f, 0.f, 0.f};

  const uint4* Wf4 = (const uint4*)Wf;

  int ar = rbase + col;
  if (ar >= Nn) ar = Nn - 1;
  const uint4* pa = (const uint4*)(Apk + (size_t)ar*HC);
  uint4 ra[8];
  #pragma unroll
  for (int ks = 0; ks < 4; ++ks) {
    ra[2*ks]   = pa[ks*8 + q*2];
    ra[2*ks+1] = pa[ks*8 + q*2 + 1];
  }

  #pragma unroll
  for (int ks = 0; ks < 4; ++ks) {
    PkAB Ah, Al;
    int cb = ks*32 + q*8;
    uint4 r0 = ra[2*ks], r1 = ra[2*ks+1];
    if (!apply_bn) {
      Ah.u[0] = (r0.x & 0xFFFFu) | (r0.y << 16);
      Al.u[0] = (r0.x >> 16)     | (r0.y & 0xFFFF0000u);
      Ah.u[1] = (r0.z & 0xFFFFu) | (r0.w << 16);
      Al.u[1] = (r0.z >> 16)     | (r0.w & 0xFFFF0000u);
      Ah.u[2] = (r1.x & 0xFFFFu) | (r1.y << 16);
      Al.u[2] = (r1.x >> 16)     | (r1.y & 0xFFFF0000u);
      Ah.u[3] = (r1.z & 0xFFFFu) | (r1.w << 16);
      Al.u[3] = (r1.z >> 16)     | (r1.w & 0xFFFF0000u);
    } else {
      float4 sc0 = *(const float4*)(scb + cb), sc1 = *(const float4*)(scb + cb + 4);
      float4 sh0 = *(const float4*)(shb + cb), sh1 = *(const float4*)(shb + cb + 4);
      float f0 = fmaxf((bflo(r0.x)+bfhi(r0.x))*sc0.x + sh0.x, 0.f);
      float f1 = fmaxf((bflo(r0.y)+bfhi(r0.y))*sc0.y + sh0.y, 0.f);
      float f2 = fmaxf((bflo(r0.z)+bfhi(r0.z))*sc0.z + sh0.z, 0.f);
      float f3 = fmaxf((bflo(r0.w)+bfhi(r0.w))*sc0.w + sh0.w, 0.f);
      float f4 = fmaxf((bflo(r1.x)+bfhi(r1.x))*sc1.x + sh1.x, 0.f);
      float f5 = fmaxf((bflo(r1.y)+bfhi(r1.y))*sc1.y + sh1.y, 0.f);
      float f6 = fmaxf((bflo(r1.z)+bfhi(r1.z))*sc1.z + sh1.z, 0.f);
      float f7 = fmaxf((bflo(r1.w)+bfhi(r1.w))*sc1.w + sh1.w, 0.f);
      u32 hb0,lb0,hb1,lb1,hb2,lb2,hb3,lb3,hb4,lb4,hb5,lb5,hb6,lb6,hb7,lb7;
      split2(f0,hb0,lb0); split2(f1,hb1,lb1); split2(f2,hb2,lb2); split2(f3,hb3,lb3);
      split2(f4,hb4,lb4); split2(f5,hb5,lb5); split2(f6,hb6,lb6); split2(f7,hb7,lb7);
      Ah.u[0] = hb0 | (hb1 << 16);  Al.u[0] = lb0 | (lb1 << 16);
      Ah.u[1] = hb2 | (hb3 << 16);  Al.u[1] = lb2 | (lb3 << 16);
      Ah.u[2] = hb4 | (hb5 << 16);  Al.u[2] = lb4 | (lb5 << 16);
      Ah.u[3] = hb6 | (hb7 << 16);  Al.u[3] = lb6 | (lb7 << 16);
    }
    #pragma unroll
    for (int nt = 0; nt < 8; ++nt) {
      uint4 b0 = Wf4[((nt*4 + ks)*2 + 0)*64 + lane];
      uint4 b1 = Wf4[((nt*4 + ks)*2 + 1)*64 + lane];
      PkAB Bh, Bl;
      Bh.u[0] = (b0.x & 0xFFFFu) | (b0.y << 16);
      Bl.u[0] = (b0.x >> 16)     | (b0.y & 0xFFFF0000u);
      Bh.u[1] = (b0.z & 0xFFFFu) | (b0.w << 16);
      Bl.u[1] = (b0.z >> 16)     | (b0.w & 0xFFFF0000u);
      Bh.u[2] = (b1.x & 0xFFFFu) | (b1.y << 16);
      Bl.u[2] = (b1.x >> 16)     | (b1.y & 0xFFFF0000u);
      Bh.u[3] = (b1.z & 0xFFFFu) | (b1.w << 16);
      Bl.u[3] = (b1.z >> 16)     | (b1.w & 0xFFFF0000u);
      acc[nt] = __builtin_amdgcn_mfma_f32_16x16x32_bf16(Ah.v, Bh.v, acc[nt], 0, 0, 0);
      acc[nt] = __builtin_amdgcn_mfma_f32_16x16x32_bf16(Ah.v, Bl.v, acc[nt], 0, 0, 0);
      acc[nt] = __builtin_amdgcn_mfma_f32_16x16x32_bf16(Al.v, Bh.v, acc[nt], 0, 0, 0);
    }
  }

  #pragma unroll
  for (int reg = 0; reg < 4; ++reg) {
    int row = rbase + q*4 + reg;
    if (row < Nn) {
      #pragma unroll
      for (int nt = 0; nt < 8; ++nt)
        C2[(size_t)row*HC + nt*16 + col] = (u16)bf16rne(acc[nt][reg]);
    }
  }

  #pragma unroll
  for (int h = 0; h < 4; ++h) {
    float a0 = aS[32*h + col], a1 = aS[32*h + 16 + col];
    float d0 = aD[32*h + col], d1 = aD[32*h + 16 + col];
    #pragma unroll
    for (int reg = 0; reg < 4; ++reg) {
      float s1 = acc[2*h][reg]*a0 + acc[2*h+1][reg]*a1;
      float s2 = acc[2*h][reg]*d0 + acc[2*h+1][reg]*d1;
      s1 += __shfl_xor(s1, 1); s1 += __shfl_xor(s1, 2);
      s1 += __shfl_xor(s1, 4); s1 += __shfl_xor(s1, 8);
      s2 += __shfl_xor(s2, 1); s2 += __shfl_xor(s2, 2);
      s2 += __shfl_xor(s2, 4); s2 += __shfl_xor(s2, 8);
      if (col == 0) {
        int row = rbase + q*4 + reg;
        if (row < Nn) {
          as_[row*NHD + h] = s1;
          ad_[row*NHD + h] = s2;
        }
      }
    }
  }
}

// CSR aggregation, 16 thr/node (uint4 gathers), 16 nodes/block;
// fused alpha->leaky->exp; packed output; per-block BN partial slot (no atomics)
__global__ __launch_bounds__(256) void aggregate(const int* __restrict__ rowp, const u32* __restrict__ rec,
                                                 const float* __restrict__ as_, const float* __restrict__ ad_,
                                                 int l, const u32* __restrict__ xl2,
                                                 const float* __restrict__ bias, u32* __restrict__ outp,
                                                 float* __restrict__ psum, float* __restrict__ psq)
{
  __shared__ float4 rsA[256], rsB[256], rqA[256], rqB[256];
  int t = threadIdx.x;
  int n = blockIdx.x * 16 + (t >> 4);
  int c8 = t & 15;                  // channels c8*8 .. c8*8+7 ; head h = c8>>2
  int h = c8 >> 2;
  float o[8];
  #pragma unroll
  for (int k = 0; k < 8; ++k) o[k] = 0.f;
  if (n < Nn) {
    int idx = l*4 + h;
    int p = idx >> 1, sel = idx & 1;
    float adh = ad_[n*NHD + h];
    int beg = rowp[n], end = rowp[n+1];
    float acc[8];
    #pragma unroll
    for (int k = 0; k < 8; ++k) acc[k] = 0.f;
    float wsum = 0.f;
    int i = beg;
    for (; i + 8 <= end; i += 8) {
      u32 eu[8]; int s[8]; float av[8]; uint4 v[8];
      #pragma unroll
      for (int j = 0; j < 8; ++j) eu[j] = rec[(size_t)(i+j)*8 + p];
      #pragma unroll
      for (int j = 0; j < 8; ++j) s[j] = (int)rec[(size_t)(i+j)*8 + 6];
      #pragma unroll
      for (int j = 0; j < 8; ++j) av[j] = as_[s[j]*NHD + h];
      #pragma unroll
      for (int j = 0; j < 8; ++j) v[j] = *(const uint4*)(xl2 + (size_t)s[j] * 64 + c8*4);
      #pragma unroll
      for (int j = 0; j < 8; ++j) {
        float ep = sel ? bfhi(eu[j]) : bflo(eu[j]);
        float a = ep + av[j] + adh;
        a = (a > 0.f) ? a : SLOPE * a;
        float wj = __expf(a);
        acc[0] += wj*bflo(v[j].x); acc[1] += wj*bfhi(v[j].x);
        acc[2] += wj*bflo(v[j].y); acc[3] += wj*bfhi(v[j].y);
        acc[4] += wj*bflo(v[j].z); acc[5] += wj*bfhi(v[j].z);
        acc[6] += wj*bflo(v[j].w); acc[7] += wj*bfhi(v[j].w);
        wsum += wj;
      }
    }
    for (; i < end; ++i) {
      u32 eu = rec[(size_t)i*8 + p];
      int s = (int)rec[(size_t)i*8 + 6];
      float ep = sel ? bfhi(eu) : bflo(eu);
      float a = ep + as_[s*NHD + h] + adh;
      a = (a > 0.f) ? a : SLOPE * a;
      float wj = __expf(a);
      uint4 v = *(const uint4*)(xl2 + (size_t)s * 64 + c8*4);
      acc[0] += wj*bflo(v.x); acc[1] += wj*bfhi(v.x);
      acc[2] += wj*bflo(v.y); acc[3] += wj*bfhi(v.y);
      acc[4] += wj*bflo(v.z); acc[5] += wj*bfhi(v.z);
      acc[6] += wj*bflo(v.w); acc[7] += wj*bfhi(v.w);
      wsum += wj;
    }
    float inv = 1.f / (wsum + 1e-16f);
    uint4 w0, w1;
    #pragma unroll
    for (int k = 0; k < 8; ++k) o[k] = acc[k]*inv + bias[c8*8 + k];
    w0.x = packsplit(o[0]); w0.y = packsplit(o[1]);
    w0.z = packsplit(o[2]); w0.w = packsplit(o[3]);
    w1.x = packsplit(o[4]); w1.y = packsplit(o[5]);
    w1.z = packsplit(o[6]); w1.w = packsplit(o[7]);
    uint4* op = (uint4*)(outp + (size_t)n * HC + c8*8);
    op[0] = w0; op[1] = w1;
  }
  rsA[t] = make_float4(o[0], o[1], o[2], o[3]);
  rsB[t] = make_float4(o[4], o[5], o[6], o[7]);
  rqA[t] = make_float4(o[0]*o[0], o[1]*o[1], o[2]*o[2], o[3]*o[3]);
  rqB[t] = make_float4(o[4]*o[4], o[5]*o[5], o[6]*o[6], o[7]*o[7]);
  __syncthreads();
  for (int off = 128; off >= 16; off >>= 1) {
    if (t < off) {
      rsA[t].x += rsA[t+off].x; rsA[t].y += rsA[t+off].y;
      rsA[t].z += rsA[t+off].z; rsA[t].w += rsA[t+off].w;
      rsB[t].x += rsB[t+off].x; rsB[t].y += rsB[t+off].y;
      rsB[t].z += rsB[t+off].z; rsB[t].w += rsB[t+off].w;
      rqA[t].x += rqA[t+off].x; rqA[t].y += rqA[t+off].y;
      rqA[t].z += rqA[t+off].z; rqA[t].w += rqA[t+off].w;
      rqB[t].x += rqB[t+off].x; rqB[t].y += rqB[t+off].y;
      rqB[t].z += rqB[t+off].z; rqB[t].w += rqB[t+off].w;
    }
    __syncthreads();
  }
  if (t < 16) {
    float4* ps = (float4*)(psum + (size_t)blockIdx.x*HC + t*8);
    ps[0] = rsA[t]; ps[1] = rsB[t];
    float4* pq = (float4*)(psq + (size_t)blockIdx.x*HC + t*8);
    pq[0] = rqA[t]; pq[1] = rqB[t];
  }
}

// coalesced column-sum of NBAG x 128 slot matrices -> gsum/gsq (few atomics)
__global__ __launch_bounds__(256) void k_bnpart(const float* __restrict__ psum, const float* __restrict__ psq,
                                                float* __restrict__ gsum, float* __restrict__ gsq)
{
  __shared__ float4 rs[256], rq[256];
  int t = threadIdx.x;
  int c4 = t & 31, rg = t >> 5;
  float4 s = make_float4(0.f,0.f,0.f,0.f), q = make_float4(0.f,0.f,0.f,0.f);
  for (int k = blockIdx.x*8 + rg; k < NBAG; k += 64*8) {
    float4 a = *(const float4*)(psum + (size_t)k*HC + c4*4);
    float4 b = *(const float4*)(psq  + (size_t)k*HC + c4*4);
    s.x += a.x; s.y += a.y; s.z += a.z; s.w += a.w;
    q.x += b.x; q.y += b.y; q.z += b.z; q.w += b.w;
  }
  rs[t] = s; rq[t] = q;
  __syncthreads();
  for (int off = 128; off >= 32; off >>= 1) {
    if (t < off) {
      rs[t].x += rs[t+off].x; rs[t].y += rs[t+off].y;
      rs[t].z += rs[t+off].z; rs[t].w += rs[t+off].w;
      rq[t].x += rq[t+off].x; rq[t].y += rq[t+off].y;
      rq[t].z += rq[t+off].z; rq[t].w += rq[t+off].w;
    }
    __syncthreads();
  }
  if (t < 32) {
    atomicAdd(&gsum[t*4+0], rs[t].x); atomicAdd(&gsum[t*4+1], rs[t].y);
    atomicAdd(&gsum[t*4+2], rs[t].z); atomicAdd(&gsum[t*4+3], rs[t].w);
    atomicAdd(&gsq[t*4+0], rq[t].x);  atomicAdd(&gsq[t*4+1], rq[t].y);
    atomicAdd(&gsq[t*4+2], rq[t].z);  atomicAdd(&gsq[t*4+3], rq[t].w);
  }
}

// finalize scale/shift; zero gsum/gsq for next layer
__global__ void k_bnfin(float* __restrict__ gsum, float* __restrict__ gsq,
                        const float* __restrict__ gammaL, const float* __restrict__ betaL,
                        float* __restrict__ scb, float* __restrict__ shb)
{
  int c = threadIdx.x;   // 128
  float s = gsum[c], q = gsq[c];
  float mu  = s * (1.f / Nn);
  float var = q * (1.f / Nn) - mu * mu;
  float sc = rsqrtf(var + BN_EPS) * gammaL[c];
  scb[c] = sc;
  shb[c] = betaL[c] - mu * sc;
  gsum[c] = 0.f; gsq[c] = 0.f;
}

// mean-pool over packed input with final-layer BN+ReLU (scb/shb)
__global__ __launch_bounds__(256) void pool2(const u32* __restrict__ Ap, const int* __restrict__ gb,
                                             const float* __restrict__ scb, const float* __restrict__ shb,
                                             float* __restrict__ pool)
{
  __shared__ float4 red[256];
  int g = blockIdx.x >> 2, qt = blockIdx.x & 3;
  int t = threadIdx.x;
  int cg = t & 7;
  int rs = t >> 3;
  int c4 = qt*8 + cg;
  int c = c4 * 4;
  int lo = gb[g], hi = gb[g+1];
  float4 s4 = *(const float4*)(scb + c);
  float4 t4 = *(const float4*)(shb + c);
  float4 acc = make_float4(0.f,0.f,0.f,0.f);
  for (int n = lo + rs; n < hi; n += 32) {
    uint4 v = *(const uint4*)(Ap + (size_t)n*HC + c);
    acc.x += fmaxf((bflo(v.x)+bfhi(v.x))*s4.x + t4.x, 0.f);
    acc.y += fmaxf((bflo(v.y)+bfhi(v.y))*s4.y + t4.y, 0.f);
    acc.z += fmaxf((bflo(v.z)+bfhi(v.z))*s4.z + t4.z, 0.f);
    acc.w += fmaxf((bflo(v.w)+bfhi(v.w))*s4.w + t4.w, 0.f);
  }
  red[t] = acc;
  __syncthreads();
  for (int off = 128; off >= 8; off >>= 1) {
    if (t < off) {
      red[t].x += red[t+off].x; red[t].y += red[t+off].y;
      red[t].z += red[t+off].z; red[t].w += red[t+off].w;
    }
    __syncthreads();
  }
  if (t < 8) {
    float inv = 1.f / fmaxf((float)(hi - lo), 1.f);
    float4 r = red[t];
    r.x *= inv; r.y *= inv; r.z *= inv; r.w *= inv;
    *(float4*)(pool + (size_t)g*HC + qt*32 + t*4) = r;
  }
}

__global__ void final_fc(const float* __restrict__ pool,
                         const float* __restrict__ fcW, const float* __restrict__ fcb,
                         float* __restrict__ out)
{
  int t = blockIdx.x * 256 + threadIdx.x;
  if (t >= Gg * NOUT) return;
  int g = t >> 1, o = t & 1;
  float acc = 0.f;
  for (int k = 0; k < HC; ++k)
    acc += pool[(size_t)g * HC + k] * fcW[k * NOUT + o];
  out[t] = acc + fcb[o];
}

extern "C" void kernel_launch(void* const* d_in, const int* in_sizes, int n_in,
                              void* d_out, int out_size, void* d_ws, size_t ws_size,
                              hipStream_t stream)
{
  const float* x      = (const float*)d_in[0];
  const int*   eidx   = (const int*)d_in[1];
  const float* eattr  = (const float*)d_in[2];
  const int*   batch  = (const int*)d_in[3];
  const float* efcW   = (const float*)d_in[4];
  const float* efcb   = (const float*)d_in[5];
  const float* Wall   = (const float*)d_in[6];
  const float* attS   = (const float*)d_in[7];
  const float* attD   = (const float*)d_in[8];
  const float* attE   = (const float*)d_in[9];
  const float* linE   = (const float*)d_in[10];
  const float* biases = (const float*)d_in[11];
  const float* gamma  = (const float*)d_in[12];
  const float* beta   = (const float*)d_in[13];
  const float* fcW    = (const float*)d_in[14];
  const float* fcb    = (const float*)d_in[15];
  float* out = (float*)d_out;

  const int* src = eidx;
  const int* dst = eidx + Ee;

  float* ws    = (float*)d_ws;
  float* bufA  = ws;                            // N*128 packed u32
  float* bufB  = bufA + (size_t)Nn*HC;          // N*128 (u16 bf16 rows use half)
  float* as_   = bufB + (size_t)Nn*HC;          // N*4
  float* ad_   = as_ + (size_t)Nn*NHD;          // N*4
  float* Kmat  = ad_ + (size_t)Nn*NHD;          // 192
  float* kb    = Kmat + 192;                    // 16
  float* scb   = kb + 16;                       // 128
  float* shb   = scb + 128;                     // 128
  float* gsum  = shb + 128;                     // 128
  float* gsq   = gsum + 128;                    // 128
  float* pool  = gsq + 128;                     // G*128 (16B-aligned)
  u32*   rec   = (u32*)(pool + (size_t)Gg*HC);  // E*8 u32 (32-B records)
  u32*   Wf    = rec + (size_t)Ee*8;            // 3*128*128 u32
  float* psum  = (float*)(Wf + 3*HC*HC);        // NBAG*128
  float* psq   = psum + (size_t)NBAG*HC;        // NBAG*128
  int*   gb    = (int*)(psq + (size_t)NBAG*HC); // Gg+1
  int*   rowp  = gb + (Gg + 3);                 // N+1
  int*   deg   = rowp + (Nn + 1);               // N
  int*   fill  = deg + Nn;                      // N (deg..fill one memset)
  int*   bsum  = fill + Nn;                     // NSB
  int*   bpre  = bsum + 128;                    // NSB

  w_split<<<(3*HC*HC + 255)/256, 256, 0, stream>>>(Wall, Wf);
  compute_K<<<1, 512, 0, stream>>>(efcW, efcb, linE, attE, Kmat, kb);
  k_gb<<<2, 256, 0, stream>>>(batch, gb);

  // CSR build + edge precompute (reused across all 3 layers)
  hipMemsetAsync(deg, 0, 2*Nn*sizeof(int), stream);
  hipMemsetAsync(gsum, 0, 256*sizeof(float), stream);
  k_hist<<<(Ee + 255)/256, 256, 0, stream>>>(dst, deg);
  k_bsum<<<NSB, 256, 0, stream>>>(deg, bsum);
  k_mid<<<1, 128, 0, stream>>>(bsum, bpre, rowp);
  k_scan<<<NSB, 256, 0, stream>>>(deg, bpre, rowp);
  k_fillpre<<<(Ee + 255)/256, 256, 0, stream>>>(src, dst, eattr, Kmat, kb, rowp, fill, rec);

  split_x<<<(Nn*HC/4 + 255)/256, 256, 0, stream>>>(x, (u32*)bufA);

  for (int l = 0; l < 3; ++l) {
    gemm_mfma<<<(Nn + 63)/64, 256, 0, stream>>>((const u32*)bufA, Wf + (size_t)l*HC*HC, (u16*)bufB,
                                                attS + l*HC, attD + l*HC, as_, ad_,
                                                scb, shb, (l > 0) ? 1 : 0);
    aggregate<<<NBAG, 256, 0, stream>>>(rowp, rec, as_, ad_, l, (const u32*)bufB,
                                        biases + l*HC, (u32*)bufA, psum, psq);
    k_bnpart<<<64, 256, 0, stream>>>(psum, psq, gsum, gsq);
    k_bnfin<<<1, 128, 0, stream>>>(gsum, gsq, gamma + l*HC, beta + l*HC, scb, shb);
  }

  pool2<<<Gg*4, 256, 0, stream>>>((const u32*)bufA, gb, scb, shb, pool);
  final_fc<<<2, 256, 0, stream>>>(pool, fcW, fcb, out);
}

// Round 15
// 610.015 us; speedup vs baseline: 1.5953x; 1.0620x over previous
//
#include <hip/hip_runtime.h>

#define Nn 100000
#define Ee 800000
#define HC 128
#define HID 32
#define NHD 4
#define EDIM 16
#define Gg 256
#define NOUT 2
#define SLOPE 0.2f
#define BN_EPS 1e-5f
#define SCHUNK 1024
#define NSB 98    // ceil(Nn/SCHUNK)
#define NBAG 6250 // ceil(Nn/16) aggregate blocks / BN slots

typedef unsigned int u32;
typedef unsigned short u16;
typedef short v8s __attribute__((ext_vector_type(8)));
typedef float v4f __attribute__((ext_vector_type(4)));

union PkAB { u32 u[4]; v8s v; };

__device__ __forceinline__ float bflo(u32 u){ return __uint_as_float(u << 16); }
__device__ __forceinline__ float bfhi(u32 u){ return __uint_as_float(u & 0xFFFF0000u); }

__device__ __forceinline__ u32 bf16rne(float x)
{
  u32 b = __float_as_uint(x);
  return (b + 0x7FFFu + ((b >> 16) & 1u)) >> 16;
}
__device__ __forceinline__ u32 packsplit(float x)
{
  u32 hb = bf16rne(x);
  float hf = __uint_as_float(hb << 16);
  u32 lb = bf16rne(x - hf);
  return hb | (lb << 16);
}
__device__ __forceinline__ void split2(float f, u32& hb, u32& lb)
{
  hb = bf16rne(f);
  lb = bf16rne(f - __uint_as_float(hb << 16));
}

// ---- tiny weight precompute: Kmat[16][12], kb[12] ----
__global__ void compute_K(const float* __restrict__ efcW, const float* __restrict__ efcb,
                          const float* __restrict__ linE, const float* __restrict__ attE,
                          float* __restrict__ Kmat, float* __restrict__ kb)
{
  __shared__ float Msh[384];
  int t = threadIdx.x;
  if (t < 384) {
    int l = t >> 7, j = (t >> 2) & 31, h = t & 3;
    float m = 0.f;
    for (int c = 0; c < 32; ++c)
      m += linE[(l*32 + j)*128 + h*32 + c] * attE[(l*4 + h)*32 + c];
    Msh[l*128 + j*4 + h] = m;
  }
  __syncthreads();
  if (t < 192) {
    int k = t / 12, col = t % 12, l = col >> 2, h = col & 3;
    float acc = 0.f;
    for (int j = 0; j < 32; ++j)
      acc += efcW[k*32 + j] * Msh[l*128 + j*4 + h];
    Kmat[k*12 + col] = acc;
  } else if (t < 204) {
    int col = t - 192, l = col >> 2, h = col & 3;
    float acc = 0.f;
    for (int j = 0; j < 32; ++j)
      acc += efcb[j] * Msh[l*128 + j*4 + h];
    kb[col] = acc;
  }
}

// ---- W -> split-bf16 MFMA B-fragment layout (once) ----
__global__ void w_split(const float* __restrict__ Wall, u32* __restrict__ Wf)
{
  int tid = blockIdx.x * 256 + threadIdx.x;
  if (tid >= 3*HC*HC) return;
  int l = tid / (HC*HC);
  int rem = tid - l*HC*HC;
  int k = rem >> 7, n = rem & 127;
  u32 p = packsplit(Wall[tid]);
  int nt = n >> 4, col = n & 15;
  int ks = k >> 5, kin = k & 31, q = kin >> 3, j = kin & 7;
  int half = j >> 2, j4 = j & 3;
  int idx = ((((l*8 + nt)*4 + ks)*2 + half)*64 + q*16 + col)*4 + j4;
  Wf[idx] = p;
}

// ---- CSR build ----
__global__ void k_hist(const int* __restrict__ dst, int* __restrict__ deg)
{
  int e = blockIdx.x * 256 + threadIdx.x;
  if (e < Ee) atomicAdd(&deg[dst[e]], 1);
}

__global__ void k_bsum(const int* __restrict__ deg, int* __restrict__ bsum)
{
  __shared__ int sh[256];
  int b = blockIdx.x, t = threadIdx.x;
  int s = 0;
  for (int i = t; i < SCHUNK; i += 256) {
    int idx = b*SCHUNK + i;
    if (idx < Nn) s += deg[idx];
  }
  sh[t] = s; __syncthreads();
  for (int o = 128; o; o >>= 1) { if (t < o) sh[t] += sh[t+o]; __syncthreads(); }
  if (!t) bsum[b] = sh[0];
}

__global__ void k_mid(const int* __restrict__ bsum, int* __restrict__ bpre, int* __restrict__ rowp)
{
  __shared__ int sh[NSB];
  int t = threadIdx.x;
  if (t < NSB) sh[t] = bsum[t];
  __syncthreads();
  if (!t) {
    int run = 0;
    for (int i = 0; i < NSB; ++i) { int v = sh[i]; sh[i] = run; run += v; }
    rowp[Nn] = run;
  }
  __syncthreads();
  if (t < NSB) bpre[t] = sh[t];
}

__global__ void k_scan(const int* __restrict__ deg, const int* __restrict__ bpre, int* __restrict__ rowp)
{
  __shared__ int sh[SCHUNK];
  int b = blockIdx.x, t = threadIdx.x;
  for (int i = t; i < SCHUNK; i += 256) {
    int idx = b*SCHUNK + i;
    sh[i] = (idx < Nn) ? deg[idx] : 0;
  }
  __syncthreads();
  if (!t) {
    int run = 0;
    for (int i = 0; i < SCHUNK; ++i) { int v = sh[i]; sh[i] = run; run += v; }
  }
  __syncthreads();
  int base = bpre[b];
  for (int i = t; i < SCHUNK; i += 256) {
    int idx = b*SCHUNK + i;
    if (idx < Nn) rowp[idx] = sh[i] + base;
  }
}

// fill + edge precompute into 32-B dst-sorted records
__global__ void k_fillpre(const int* __restrict__ src, const int* __restrict__ dst,
                          const float* __restrict__ eattr,
                          const float* __restrict__ Kmat, const float* __restrict__ kb,
                          const int* __restrict__ rowp, int* __restrict__ fill,
                          u32* __restrict__ rec)
{
  int e = blockIdx.x * 256 + threadIdx.x;
  if (e >= Ee) return;
  const float4* p = (const float4*)(eattr + (size_t)e * EDIM);
  float ea[16];
  #pragma unroll
  for (int qq = 0; qq < 4; ++qq) {
    float4 v = p[qq];
    ea[qq*4+0] = v.x; ea[qq*4+1] = v.y; ea[qq*4+2] = v.z; ea[qq*4+3] = v.w;
  }
  float ep[12];
  #pragma unroll
  for (int col = 0; col < 12; ++col) ep[col] = kb[col];
  #pragma unroll
  for (int k = 0; k < 16; ++k) {
    float v = ea[k];
    #pragma unroll
    for (int col = 0; col < 12; ++col) ep[col] += v * Kmat[k*12 + col];
  }
  int d = dst[e];
  int pos = rowp[d] + atomicAdd(&fill[d], 1);
  uint4 r0, r1;
  r0.x = bf16rne(ep[0])  | (bf16rne(ep[1])  << 16);
  r0.y = bf16rne(ep[2])  | (bf16rne(ep[3])  << 16);
  r0.z = bf16rne(ep[4])  | (bf16rne(ep[5])  << 16);
  r0.w = bf16rne(ep[6])  | (bf16rne(ep[7])  << 16);
  r1.x = bf16rne(ep[8])  | (bf16rne(ep[9])  << 16);
  r1.y = bf16rne(ep[10]) | (bf16rne(ep[11]) << 16);
  r1.z = (u32)src[e];
  r1.w = 0;
  uint4* rp = (uint4*)(rec + (size_t)pos * 8);
  rp[0] = r0; rp[1] = r1;
}

__device__ __forceinline__ int lbound(const int* __restrict__ a, int n, int key)
{
  int lo = 0, hi = n;
  while (lo < hi) {
    int mid = (lo + hi) >> 1;
    if (a[mid] < key) lo = mid + 1; else hi = mid;
  }
  return lo;
}

__global__ void k_gb(const int* __restrict__ batch, int* __restrict__ gb)
{
  int g = blockIdx.x * 256 + threadIdx.x;
  if (g <= Gg) gb[g] = lbound(batch, Nn, g);
}

// pack x (no BN) once
__global__ void split_x(const float* __restrict__ src, u32* __restrict__ dst)
{
  int idx = blockIdx.x * 256 + threadIdx.x;
  if (idx >= Nn*HC/4) return;
  float4 v = ((const float4*)src)[idx];
  uint4 o;
  o.x = packsplit(v.x); o.y = packsplit(v.y);
  o.z = packsplit(v.z); o.w = packsplit(v.w);
  ((uint4*)dst)[idx] = o;
}

// ---- MFMA GEMM, 64-row blocks; B ks-slice staged in 16 KB LDS;
// BN+ReLU of prev layer at A-load; C as bf16; attn dots fused.
__global__ __launch_bounds__(256, 4) void gemm_mfma(const u32* __restrict__ Apk,
                                                    const u32* __restrict__ Wf,
                                                    u16* __restrict__ C2,
                                                    const float* __restrict__ aS,
                                                    const float* __restrict__ aD,
                                                    float* __restrict__ as_,
                                                    float* __restrict__ ad_,
                                                    const float* __restrict__ scb,
                                                    const float* __restrict__ shb,
                                                    int apply_bn)
{
  __shared__ uint4 Bsh[1024];   // 16 KB: [nt(8)][half(2)][lane(64)]
  int t = threadIdx.x;
  int w = t >> 6, lane = t & 63;
  int col = lane & 15, q = lane >> 4;
  int rbase = blockIdx.x * 64 + w * 16;

  v4f acc[8];
  #pragma unroll
  for (int nt = 0; nt < 8; ++nt) acc[nt] = (v4f){0.f, 0.f, 0.f, 0.f};

  const uint4* Wf4 = (const uint4*)Wf;

  int ar = rbase + col;
  if (ar >= Nn) ar = Nn - 1;
  const uint4* pa = (const uint4*)(Apk + (size_t)ar*HC);
  uint4 ra[8];
  #pragma unroll
  for (int ks = 0; ks < 4; ++ks) {
    ra[2*ks]   = pa[ks*8 + q*2];
    ra[2*ks+1] = pa[ks*8 + q*2 + 1];
  }

  for (int ks = 0; ks < 4; ++ks) {
    // stage B ks-slice: 1024 uint4 (8 nt x 2 half x 64 lane)
    #pragma unroll
    for (int i = 0; i < 4; ++i) {
      int u = t + i*256;
      int nt = u >> 7, rem = u & 127;
      Bsh[u] = Wf4[((nt*4 + ks)*2 + (rem >> 6))*64 + (rem & 63)];
    }
    __syncthreads();

    PkAB Ah, Al;
    int cb = ks*32 + q*8;
    uint4 r0 = ra[2*ks], r1 = ra[2*ks+1];
    if (!apply_bn) {
      Ah.u[0] = (r0.x & 0xFFFFu) | (r0.y << 16);
      Al.u[0] = (r0.x >> 16)     | (r0.y & 0xFFFF0000u);
      Ah.u[1] = (r0.z & 0xFFFFu) | (r0.w << 16);
      Al.u[1] = (r0.z >> 16)     | (r0.w & 0xFFFF0000u);
      Ah.u[2] = (r1.x & 0xFFFFu) | (r1.y << 16);
      Al.u[2] = (r1.x >> 16)     | (r1.y & 0xFFFF0000u);
      Ah.u[3] = (r1.z & 0xFFFFu) | (r1.w << 16);
      Al.u[3] = (r1.z >> 16)     | (r1.w & 0xFFFF0000u);
    } else {
      float4 sc0 = *(const float4*)(scb + cb), sc1 = *(const float4*)(scb + cb + 4);
      float4 sh0 = *(const float4*)(shb + cb), sh1 = *(const float4*)(shb + cb + 4);
      float f0 = fmaxf((bflo(r0.x)+bfhi(r0.x))*sc0.x + sh0.x, 0.f);
      float f1 = fmaxf((bflo(r0.y)+bfhi(r0.y))*sc0.y + sh0.y, 0.f);
      float f2 = fmaxf((bflo(r0.z)+bfhi(r0.z))*sc0.z + sh0.z, 0.f);
      float f3 = fmaxf((bflo(r0.w)+bfhi(r0.w))*sc0.w + sh0.w, 0.f);
      float f4 = fmaxf((bflo(r1.x)+bfhi(r1.x))*sc1.x + sh1.x, 0.f);
      float f5 = fmaxf((bflo(r1.y)+bfhi(r1.y))*sc1.y + sh1.y, 0.f);
      float f6 = fmaxf((bflo(r1.z)+bfhi(r1.z))*sc1.z + sh1.z, 0.f);
      float f7 = fmaxf((bflo(r1.w)+bfhi(r1.w))*sc1.w + sh1.w, 0.f);
      u32 hb0,lb0,hb1,lb1,hb2,lb2,hb3,lb3,hb4,lb4,hb5,lb5,hb6,lb6,hb7,lb7;
      split2(f0,hb0,lb0); split2(f1,hb1,lb1); split2(f2,hb2,lb2); split2(f3,hb3,lb3);
      split2(f4,hb4,lb4); split2(f5,hb5,lb5); split2(f6,hb6,lb6); split2(f7,hb7,lb7);
      Ah.u[0] = hb0 | (hb1 << 16);  Al.u[0] = lb0 | (lb1 << 16);
      Ah.u[1] = hb2 | (hb3 << 16);  Al.u[1] = lb2 | (lb3 << 16);
      Ah.u[2] = hb4 | (hb5 << 16);  Al.u[2] = lb4 | (lb5 << 16);
      Ah.u[3] = hb6 | (hb7 << 16);  Al.u[3] = lb6 | (lb7 << 16);
    }
    #pragma unroll
    for (int nt = 0; nt < 8; ++nt) {
      uint4 b0 = Bsh[nt*128 + lane];
      uint4 b1 = Bsh[nt*128 + 64 + lane];
      PkAB Bh, Bl;
      Bh.u[0] = (b0.x & 0xFFFFu) | (b0.y << 16);
      Bl.u[0] = (b0.x >> 16)     | (b0.y & 0xFFFF0000u);
      Bh.u[1] = (b0.z & 0xFFFFu) | (b0.w << 16);
      Bl.u[1] = (b0.z >> 16)     | (b0.w & 0xFFFF0000u);
      Bh.u[2] = (b1.x & 0xFFFFu) | (b1.y << 16);
      Bl.u[2] = (b1.x >> 16)     | (b1.y & 0xFFFF0000u);
      Bh.u[3] = (b1.z & 0xFFFFu) | (b1.w << 16);
      Bl.u[3] = (b1.z >> 16)     | (b1.w & 0xFFFF0000u);
      acc[nt] = __builtin_amdgcn_mfma_f32_16x16x32_bf16(Ah.v, Bh.v, acc[nt], 0, 0, 0);
      acc[nt] = __builtin_amdgcn_mfma_f32_16x16x32_bf16(Ah.v, Bl.v, acc[nt], 0, 0, 0);
      acc[nt] = __builtin_amdgcn_mfma_f32_16x16x32_bf16(Al.v, Bh.v, acc[nt], 0, 0, 0);
    }
    __syncthreads();
  }

  #pragma unroll
  for (int reg = 0; reg < 4; ++reg) {
    int row = rbase + q*4 + reg;
    if (row < Nn) {
      #pragma unroll
      for (int nt = 0; nt < 8; ++nt)
        C2[(size_t)row*HC + nt*16 + col] = (u16)bf16rne(acc[nt][reg]);
    }
  }

  #pragma unroll
  for (int h = 0; h < 4; ++h) {
    float a0 = aS[32*h + col], a1 = aS[32*h + 16 + col];
    float d0 = aD[32*h + col], d1 = aD[32*h + 16 + col];
    #pragma unroll
    for (int reg = 0; reg < 4; ++reg) {
      float s1 = acc[2*h][reg]*a0 + acc[2*h+1][reg]*a1;
      float s2 = acc[2*h][reg]*d0 + acc[2*h+1][reg]*d1;
      s1 += __shfl_xor(s1, 1); s1 += __shfl_xor(s1, 2);
      s1 += __shfl_xor(s1, 4); s1 += __shfl_xor(s1, 8);
      s2 += __shfl_xor(s2, 1); s2 += __shfl_xor(s2, 2);
      s2 += __shfl_xor(s2, 4); s2 += __shfl_xor(s2, 8);
      if (col == 0) {
        int row = rbase + q*4 + reg;
        if (row < Nn) {
          as_[row*NHD + h] = s1;
          ad_[row*NHD + h] = s2;
        }
      }
    }
  }
}

// CSR aggregation, 16 thr/node (uint4 gathers), 16 nodes/block;
// fused alpha->leaky->exp; packed output; per-block BN partial slot (no atomics)
__global__ __launch_bounds__(256) void aggregate(const int* __restrict__ rowp, const u32* __restrict__ rec,
                                                 const float* __restrict__ as_, const float* __restrict__ ad_,
                                                 int l, const u32* __restrict__ xl2,
                                                 const float* __restrict__ bias, u32* __restrict__ outp,
                                                 float* __restrict__ psum, float* __restrict__ psq)
{
  __shared__ float4 rsA[256], rsB[256], rqA[256], rqB[256];
  int t = threadIdx.x;
  int n = blockIdx.x * 16 + (t >> 4);
  int c8 = t & 15;                  // channels c8*8 .. c8*8+7 ; head h = c8>>2
  int h = c8 >> 2;
  float o[8];
  #pragma unroll
  for (int k = 0; k < 8; ++k) o[k] = 0.f;
  if (n < Nn) {
    int idx = l*4 + h;
    int p = idx >> 1, sel = idx & 1;
    float adh = ad_[n*NHD + h];
    int beg = rowp[n], end = rowp[n+1];
    float acc[8];
    #pragma unroll
    for (int k = 0; k < 8; ++k) acc[k] = 0.f;
    float wsum = 0.f;
    int i = beg;
    for (; i + 8 <= end; i += 8) {
      u32 eu[8]; int s[8]; float av[8]; uint4 v[8];
      #pragma unroll
      for (int j = 0; j < 8; ++j) eu[j] = rec[(size_t)(i+j)*8 + p];
      #pragma unroll
      for (int j = 0; j < 8; ++j) s[j] = (int)rec[(size_t)(i+j)*8 + 6];
      #pragma unroll
      for (int j = 0; j < 8; ++j) av[j] = as_[s[j]*NHD + h];
      #pragma unroll
      for (int j = 0; j < 8; ++j) v[j] = *(const uint4*)(xl2 + (size_t)s[j] * 64 + c8*4);
      #pragma unroll
      for (int j = 0; j < 8; ++j) {
        float ep = sel ? bfhi(eu[j]) : bflo(eu[j]);
        float a = ep + av[j] + adh;
        a = (a > 0.f) ? a : SLOPE * a;
        float wj = __expf(a);
        acc[0] += wj*bflo(v[j].x); acc[1] += wj*bfhi(v[j].x);
        acc[2] += wj*bflo(v[j].y); acc[3] += wj*bfhi(v[j].y);
        acc[4] += wj*bflo(v[j].z); acc[5] += wj*bfhi(v[j].z);
        acc[6] += wj*bflo(v[j].w); acc[7] += wj*bfhi(v[j].w);
        wsum += wj;
      }
    }
    for (; i + 4 <= end; i += 4) {
      u32 eu[4]; int s[4]; float av[4]; uint4 v[4];
      #pragma unroll
      for (int j = 0; j < 4; ++j) eu[j] = rec[(size_t)(i+j)*8 + p];
      #pragma unroll
      for (int j = 0; j < 4; ++j) s[j] = (int)rec[(size_t)(i+j)*8 + 6];
      #pragma unroll
      for (int j = 0; j < 4; ++j) av[j] = as_[s[j]*NHD + h];
      #pragma unroll
      for (int j = 0; j < 4; ++j) v[j] = *(const uint4*)(xl2 + (size_t)s[j] * 64 + c8*4);
      #pragma unroll
      for (int j = 0; j < 4; ++j) {
        float ep = sel ? bfhi(eu[j]) : bflo(eu[j]);
        float a = ep + av[j] + adh;
        a = (a > 0.f) ? a : SLOPE * a;
        float wj = __expf(a);
        acc[0] += wj*bflo(v[j].x); acc[1] += wj*bfhi(v[j].x);
        acc[2] += wj*bflo(v[j].y); acc[3] += wj*bfhi(v[j].y);
        acc[4] += wj*bflo(v[j].z); acc[5] += wj*bfhi(v[j].z);
        acc[6] += wj*bflo(v[j].w); acc[7] += wj*bfhi(v[j].w);
        wsum += wj;
      }
    }
    for (; i < end; ++i) {
      u32 eu = rec[(size_t)i*8 + p];
      int s = (int)rec[(size_t)i*8 + 6];
      float ep = sel ? bfhi(eu) : bflo(eu);
      float a = ep + as_[s*NHD + h] + adh;
      a = (a > 0.f) ? a : SLOPE * a;
      float wj = __expf(a);
      uint4 v = *(const uint4*)(xl2 + (size_t)s * 64 + c8*4);
      acc[0] += wj*bflo(v.x); acc[1] += wj*bfhi(v.x);
      acc[2] += wj*bflo(v.y); acc[3] += wj*bfhi(v.y);
      acc[4] += wj*bflo(v.z); acc[5] += wj*bfhi(v.z);
      acc[6] += wj*bflo(v.w); acc[7] += wj*bfhi(v.w);
      wsum += wj;
    }
    float inv = 1.f / (wsum + 1e-16f);
    uint4 w0, w1;
    #pragma unroll
    for (int k = 0; k < 8; ++k) o[k] = acc[k]*inv + bias[c8*8 + k];
    w0.x = packsplit(o[0]); w0.y = packsplit(o[1]);
    w0.z = packsplit(o[2]); w0.w = packsplit(o[3]);
    w1.x = packsplit(o[4]); w1.y = packsplit(o[5]);
    w1.z = packsplit(o[6]); w1.w = packsplit(o[7]);
    uint4* op = (uint4*)(outp + (size_t)n * HC + c8*8);
    op[0] = w0; op[1] = w1;
  }
  rsA[t] = make_float4(o[0], o[1], o[2], o[3]);
  rsB[t] = make_float4(o[4], o[5], o[6], o[7]);
  rqA[t] = make_float4(o[0]*o[0], o[1]*o[1], o[2]*o[2], o[3]*o[3]);
  rqB[t] = make_float4(o[4]*o[4], o[5]*o[5], o[6]*o[6], o[7]*o[7]);
  __syncthreads();
  for (int off = 128; off >= 16; off >>= 1) {
    if (t < off) {
      rsA[t].x += rsA[t+off].x; rsA[t].y += rsA[t+off].y;
      rsA[t].z += rsA[t+off].z; rsA[t].w += rsA[t+off].w;
      rsB[t].x += rsB[t+off].x; rsB[t].y += rsB[t+off].y;
      rsB[t].z += rsB[t+off].z; rsB[t].w += rsB[t+off].w;
      rqA[t].x += rqA[t+off].x; rqA[t].y += rqA[t+off].y;
      rqA[t].z += rqA[t+off].z; rqA[t].w += rqA[t+off].w;
      rqB[t].x += rqB[t+off].x; rqB[t].y += rqB[t+off].y;
      rqB[t].z += rqB[t+off].z; rqB[t].w += rqB[t+off].w;
    }
    __syncthreads();
  }
  if (t < 16) {
    float4* ps = (float4*)(psum + (size_t)blockIdx.x*HC + t*8);
    ps[0] = rsA[t]; ps[1] = rsB[t];
    float4* pq = (float4*)(psq + (size_t)blockIdx.x*HC + t*8);
    pq[0] = rqA[t]; pq[1] = rqB[t];
  }
}

// coalesced column-sum of NBAG x 128 slot matrices -> gsum/gsq (few atomics)
__global__ __launch_bounds__(256) void k_bnpart(const float* __restrict__ psum, const float* __restrict__ psq,
                                                float* __restrict__ gsum, float* __restrict__ gsq)
{
  __shared__ float4 rs[256], rq[256];
  int t = threadIdx.x;
  int c4 = t & 31, rg = t >> 5;
  float4 s = make_float4(0.f,0.f,0.f,0.f), q = make_float4(0.f,0.f,0.f,0.f);
  for (int k = blockIdx.x*8 + rg; k < NBAG; k += 64*8) {
    float4 a = *(const float4*)(psum + (size_t)k*HC + c4*4);
    float4 b = *(const float4*)(psq  + (size_t)k*HC + c4*4);
    s.x += a.x; s.y += a.y; s.z += a.z; s.w += a.w;
    q.x += b.x; q.y += b.y; q.z += b.z; q.w += b.w;
  }
  rs[t] = s; rq[t] = q;
  __syncthreads();
  for (int off = 128; off >= 32; off >>= 1) {
    if (t < off) {
      rs[t].x += rs[t+off].x; rs[t].y += rs[t+off].y;
      rs[t].z += rs[t+off].z; rs[t].w += rs[t+off].w;
      rq[t].x += rq[t+off].x; rq[t].y += rq[t+off].y;
      rq[t].z += rq[t+off].z; rq[t].w += rq[t+off].w;
    }
    __syncthreads();
  }
  if (t < 32) {
    atomicAdd(&gsum[t*4+0], rs[t].x); atomicAdd(&gsum[t*4+1], rs[t].y);
    atomicAdd(&gsum[t*4+2], rs[t].z); atomicAdd(&gsum[t*4+3], rs[t].w);
    atomicAdd(&gsq[t*4+0], rq[t].x);  atomicAdd(&gsq[t*4+1], rq[t].y);
    atomicAdd(&gsq[t*4+2], rq[t].z);  atomicAdd(&gsq[t*4+3], rq[t].w);
  }
}

// finalize scale/shift; zero gsum/gsq for next layer
__global__ void k_bnfin(float* __restrict__ gsum, float* __restrict__ gsq,
                        const float* __restrict__ gammaL, const float* __restrict__ betaL,
                        float* __restrict__ scb, float* __restrict__ shb)
{
  int c = threadIdx.x;   // 128
  float s = gsum[c], q = gsq[c];
  float mu  = s * (1.f / Nn);
  float var = q * (1.f / Nn) - mu * mu;
  float sc = rsqrtf(var + BN_EPS) * gammaL[c];
  scb[c] = sc;
  shb[c] = betaL[c] - mu * sc;
  gsum[c] = 0.f; gsq[c] = 0.f;
}

// mean-pool over packed input with final-layer BN+ReLU (scb/shb)
__global__ __launch_bounds__(256) void pool2(const u32* __restrict__ Ap, const int* __restrict__ gb,
                                             const float* __restrict__ scb, const float* __restrict__ shb,
                                             float* __restrict__ pool)
{
  __shared__ float4 red[256];
  int g = blockIdx.x >> 2, qt = blockIdx.x & 3;
  int t = threadIdx.x;
  int cg = t & 7;
  int rs = t >> 3;
  int c4 = qt*8 + cg;
  int c = c4 * 4;
  int lo = gb[g], hi = gb[g+1];
  float4 s4 = *(const float4*)(scb + c);
  float4 t4 = *(const float4*)(shb + c);
  float4 acc = make_float4(0.f,0.f,0.f,0.f);
  for (int n = lo + rs; n < hi; n += 32) {
    uint4 v = *(const uint4*)(Ap + (size_t)n*HC + c);
    acc.x += fmaxf((bflo(v.x)+bfhi(v.x))*s4.x + t4.x, 0.f);
    acc.y += fmaxf((bflo(v.y)+bfhi(v.y))*s4.y + t4.y, 0.f);
    acc.z += fmaxf((bflo(v.z)+bfhi(v.z))*s4.z + t4.z, 0.f);
    acc.w += fmaxf((bflo(v.w)+bfhi(v.w))*s4.w + t4.w, 0.f);
  }
  red[t] = acc;
  __syncthreads();
  for (int off = 128; off >= 8; off >>= 1) {
    if (t < off) {
      red[t].x += red[t+off].x; red[t].y += red[t+off].y;
      red[t].z += red[t+off].z; red[t].w += red[t+off].w;
    }
    __syncthreads();
  }
  if (t < 8) {
    float inv = 1.f / fmaxf((float)(hi - lo), 1.f);
    float4 r = red[t];
    r.x *= inv; r.y *= inv; r.z *= inv; r.w *= inv;
    *(float4*)(pool + (size_t)g*HC + qt*32 + t*4) = r;
  }
}

__global__ void final_fc(const float* __restrict__ pool,
                         const float* __restrict__ fcW, const float* __restrict__ fcb,
                         float* __restrict__ out)
{
  int t = blockIdx.x * 256 + threadIdx.x;
  if (t >= Gg * NOUT) return;
  int g = t >> 1, o = t & 1;
  float acc = 0.f;
  for (int k = 0; k < HC; ++k)
    acc += pool[(size_t)g * HC + k] * fcW[k * NOUT + o];
  out[t] = acc + fcb[o];
}

extern "C" void kernel_launch(void* const* d_in, const int* in_sizes, int n_in,
                              void* d_out, int out_size, void* d_ws, size_t ws_size,
                              hipStream_t stream)
{
  const float* x      = (const float*)d_in[0];
  const int*   eidx   = (const int*)d_in[1];
  const float* eattr  = (const float*)d_in[2];
  const int*   batch  = (const int*)d_in[3];
  const float* efcW   = (const float*)d_in[4];
  const float* efcb   = (const float*)d_in[5];
  const float* Wall   = (const float*)d_in[6];
  const float* attS   = (const float*)d_in[7];
  const float* attD   = (const float*)d_in[8];
  const float* attE   = (const float*)d_in[9];
  const float* linE   = (const float*)d_in[10];
  const float* biases = (const float*)d_in[11];
  const float* gamma  = (const float*)d_in[12];
  const float* beta   = (const float*)d_in[13];
  const float* fcW    = (const float*)d_in[14];
  const float* fcb    = (const float*)d_in[15];
  float* out = (float*)d_out;

  const int* src = eidx;
  const int* dst = eidx + Ee;

  float* ws    = (float*)d_ws;
  float* bufA  = ws;                            // N*128 packed u32
  float* bufB  = bufA + (size_t)Nn*HC;          // N*128 (u16 bf16 rows use half)
  float* as_   = bufB + (size_t)Nn*HC;          // N*4
  float* ad_   = as_ + (size_t)Nn*NHD;          // N*4
  float* Kmat  = ad_ + (size_t)Nn*NHD;          // 192
  float* kb    = Kmat + 192;                    // 16
  float* scb   = kb + 16;                       // 128
  float* shb   = scb + 128;                     // 128
  float* gsum  = shb + 128;                     // 128
  float* gsq   = gsum + 128;                    // 128
  float* pool  = gsq + 128;                     // G*128 (16B-aligned)
  u32*   rec   = (u32*)(pool + (size_t)Gg*HC);  // E*8 u32 (32-B records)
  u32*   Wf    = rec + (size_t)Ee*8;            // 3*128*128 u32
  float* psum  = (float*)(Wf + 3*HC*HC);        // NBAG*128
  float* psq   = psum + (size_t)NBAG*HC;        // NBAG*128
  int*   gb    = (int*)(psq + (size_t)NBAG*HC); // Gg+1
  int*   rowp  = gb + (Gg + 3);                 // N+1
  int*   deg   = rowp + (Nn + 1);               // N
  int*   fill  = deg + Nn;                      // N (deg..fill one memset)
  int*   bsum  = fill + Nn;                     // NSB
  int*   bpre  = bsum + 128;                    // NSB

  w_split<<<(3*HC*HC + 255)/256, 256, 0, stream>>>(Wall, Wf);
  compute_K<<<1, 512, 0, stream>>>(efcW, efcb, linE, attE, Kmat, kb);
  k_gb<<<2, 256, 0, stream>>>(batch, gb);

  // CSR build + edge precompute (reused across all 3 layers)
  hipMemsetAsync(deg, 0, 2*Nn*sizeof(int), stream);
  hipMemsetAsync(gsum, 0, 256*sizeof(float), stream);
  k_hist<<<(Ee + 255)/256, 256, 0, stream>>>(dst, deg);
  k_bsum<<<NSB, 256, 0, stream>>>(deg, bsum);
  k_mid<<<1, 128, 0, stream>>>(bsum, bpre, rowp);
  k_scan<<<NSB, 256, 0, stream>>>(deg, bpre, rowp);
  k_fillpre<<<(Ee + 255)/256, 256, 0, stream>>>(src, dst, eattr, Kmat, kb, rowp, fill, rec);

  split_x<<<(Nn*HC/4 + 255)/256, 256, 0, stream>>>(x, (u32*)bufA);

  for (int l = 0; l < 3; ++l) {
    gemm_mfma<<<(Nn + 63)/64, 256, 0, stream>>>((const u32*)bufA, Wf + (size_t)l*HC*HC, (u16*)bufB,
                                                attS + l*HC, attD + l*HC, as_, ad_,
                                                scb, shb, (l > 0) ? 1 : 0);
    aggregate<<<NBAG, 256, 0, stream>>>(rowp, rec, as_, ad_, l, (const u32*)bufB,
                                        biases + l*HC, (u32*)bufA, psum, psq);
    k_bnpart<<<64, 256, 0, stream>>>(psum, psq, gsum, gsq);
    k_bnfin<<<1, 128, 0, stream>>>(gsum, gsq, gamma + l*HC, beta + l*HC, scb, shb);
  }

  pool2<<<Gg*4, 256, 0, stream>>>((const u32*)bufA, gb, scb, shb, pool);
  final_fc<<<2, 256, 0, stream>>>(pool, fcW, fcb, out);
}